// Round 1
// baseline (339.387 us; speedup 1.0000x reference)
//
#include <hip/hip_runtime.h>
#include <hip/hip_bf16.h>
#include <math.h>

using f32x4 = __attribute__((ext_vector_type(4))) float;
using s16x8 = __attribute__((ext_vector_type(8))) short;
using s16x4 = __attribute__((ext_vector_type(4))) short;

#define HD 64
#define NH 16
#define TT 2048
#define DIN 1024
#define NB 2
#define M_TOK (NB*TT)   // 4096
#define PADK 40         // 32-elem K-slab padded to 40 (80B rows, 16B aligned, conflict-light)

__device__ __forceinline__ ushort f2b(float f) {
  union { float f; unsigned u; } v; v.f = f;
  unsigned u = v.u;
  return (ushort)((u + 0x7FFFu + ((u >> 16) & 1u)) >> 16);  // RNE
}

// ---------- conversions ----------
__global__ __launch_bounds__(256) void cvt_f32_bf16(const float* __restrict__ in,
                                                    ushort* __restrict__ out, int n8) {
  int i = blockIdx.x * 256 + threadIdx.x;
  if (i >= n8) return;
  const f32x4* p = (const f32x4*)(in + (size_t)i * 8);
  f32x4 a = p[0], b = p[1];
  s16x8 o;
  o[0]=(short)f2b(a[0]); o[1]=(short)f2b(a[1]); o[2]=(short)f2b(a[2]); o[3]=(short)f2b(a[3]);
  o[4]=(short)f2b(b[0]); o[5]=(short)f2b(b[1]); o[6]=(short)f2b(b[2]); o[7]=(short)f2b(b[3]);
  *(s16x8*)(out + (size_t)i * 8) = o;
}

// Wt[n][k] = W[k][n], bf16
__global__ __launch_bounds__(256) void transpose_cvt(const float* __restrict__ W,
                                                     ushort* __restrict__ Wt, int K, int N) {
  __shared__ float tile[32][33];
  int nb = blockIdx.x * 32, kb = blockIdx.y * 32;
  int tx = threadIdx.x & 31, ty = threadIdx.x >> 5;  // 32 x 8
  #pragma unroll
  for (int j = ty; j < 32; j += 8) tile[j][tx] = W[(size_t)(kb + j) * N + nb + tx];
  __syncthreads();
  #pragma unroll
  for (int j = ty; j < 32; j += 8) Wt[(size_t)(nb + j) * K + kb + tx] = f2b(tile[tx][j]);
}

// ---------- fused QKV projection GEMM ----------
// C[4096 x 3072] = Xb[4096 x 1024] @ W[1024 x 3072]  (W given as Wt[n][k])
// n in [0,1024): Q (scaled 1/8) -> Qb[b][h][t][d]
// n in [1024,2048): K          -> Kb[b][h][t][d]
// n in [2048,3072): V          -> Vt[b][h][d][t]   (transposed for attention PV B-frags)
__global__ __launch_bounds__(256) void gemm_qkv(const ushort* __restrict__ Xb,
                                                const ushort* __restrict__ Wt,
                                                ushort* __restrict__ Qb,
                                                ushort* __restrict__ Kb,
                                                ushort* __restrict__ Vt) {
  __shared__ ushort Al[128 * PADK];
  __shared__ ushort Bl[128 * PADK];
  int tid = threadIdx.x, lane = tid & 63, wid = tid >> 6;
  int wr = wid >> 1, wc = wid & 1, g = lane >> 4, c = lane & 15;
  int m0 = blockIdx.y * 128, n0 = blockIdx.x * 128;
  f32x4 acc[4][4] = {};
  for (int k0 = 0; k0 < DIN; k0 += 32) {
    __syncthreads();
    #pragma unroll
    for (int j = 0; j < 2; ++j) {
      int ci = tid + j * 256;           // 512 chunks of 16B per matrix
      int row = ci >> 2, part = ci & 3;
      *(s16x8*)&Al[row * PADK + part * 8] =
          *(const s16x8*)&Xb[(size_t)(m0 + row) * DIN + k0 + part * 8];
      *(s16x8*)&Bl[row * PADK + part * 8] =
          *(const s16x8*)&Wt[(size_t)(n0 + row) * DIN + k0 + part * 8];
    }
    __syncthreads();
    s16x8 af[4], bfr[4];
    #pragma unroll
    for (int i = 0; i < 4; ++i) {
      af[i]  = *(const s16x8*)&Al[(wr * 64 + i * 16 + c) * PADK + g * 8];
      bfr[i] = *(const s16x8*)&Bl[(wc * 64 + i * 16 + c) * PADK + g * 8];
    }
    #pragma unroll
    for (int i = 0; i < 4; ++i)
      #pragma unroll
      for (int jn = 0; jn < 4; ++jn)
        acc[i][jn] = __builtin_amdgcn_mfma_f32_16x16x32_bf16(af[i], bfr[jn], acc[i][jn], 0, 0, 0);
  }
  #pragma unroll
  for (int i = 0; i < 4; ++i)
    #pragma unroll
    for (int jn = 0; jn < 4; ++jn) {
      int mrow = m0 + wr * 64 + i * 16 + g * 4;      // rows mrow..mrow+3 (consecutive t)
      int n = n0 + wc * 64 + jn * 16 + c;
      int b = mrow >> 11, t = mrow & (TT - 1);
      int which = n >> 10, nn = n & 1023, h = nn >> 6, d = nn & 63;
      size_t bh = (size_t)(b * NH + h);
      if (which == 2) {                              // V -> Vt[b][h][d][t], 4 consecutive t -> 8B store
        s16x4 pk;
        pk[0]=(short)f2b(acc[i][jn][0]); pk[1]=(short)f2b(acc[i][jn][1]);
        pk[2]=(short)f2b(acc[i][jn][2]); pk[3]=(short)f2b(acc[i][jn][3]);
        *(s16x4*)&Vt[(bh * HD + d) * TT + t] = pk;
      } else {
        float sc = (which == 0) ? 0.125f : 1.0f;     // fold softmax scale into Q
        ushort* dst = (which == 0) ? &Qb[(bh * TT + t) * HD + d]
                                   : &Kb[(bh * TT + t) * HD + d];
        #pragma unroll
        for (int r = 0; r < 4; ++r) dst[(size_t)r * HD] = f2b(acc[i][jn][r] * sc);
      }
    }
}

// ---------- causal flash attention ----------
// grid: (T/64, B*H); block 256 = 4 waves, each wave owns 16 q-rows.
__global__ __launch_bounds__(256) void attn_fwd(const ushort* __restrict__ Qb,
                                                const ushort* __restrict__ Kb,
                                                const ushort* __restrict__ Vt,
                                                ushort* __restrict__ Ctx) {
  __shared__ ushort Kl[32 * 72];      // [kv=32][d=64] padded to 72
  __shared__ ushort Vl[64 * PADK];    // [d=64][kv=32] padded to 40
  __shared__ ushort Pl[4][16 * PADK]; // per-wave P tile [q=16][kv=32] padded
  int bh = blockIdx.y;
  int q0 = blockIdx.x * 64;
  const ushort* Qh = Qb + (size_t)bh * TT * HD;
  const ushort* Kh = Kb + (size_t)bh * TT * HD;
  const ushort* Vh = Vt + (size_t)bh * HD * TT;
  int tid = threadIdx.x, lane = tid & 63, w = tid >> 6, g = lane >> 4, c = lane & 15;

  s16x8 qf[2];
  #pragma unroll
  for (int ds = 0; ds < 2; ++ds)
    qf[ds] = *(const s16x8*)&Qh[(size_t)(q0 + w * 16 + c) * HD + ds * 32 + g * 8];

  f32x4 ctx[4] = {};
  float mrun[4], lrun[4];
  #pragma unroll
  for (int r = 0; r < 4; ++r) { mrun[r] = -INFINITY; lrun[r] = 0.f; }
  int qrow = q0 + w * 16 + g * 4;     // D-layout row base for this lane

  for (int kv = 0; kv < q0 + 64; kv += 32) {
    __syncthreads();
    {
      int row = tid >> 3, part = tid & 7;   // K tile: 32 rows x 64 d
      *(s16x8*)&Kl[row * 72 + part * 8] =
          *(const s16x8*)&Kh[(size_t)(kv + row) * HD + part * 8];
      int vrow = tid >> 2, vpart = tid & 3; // Vt tile: 64 rows(d) x 32 t
      *(s16x8*)&Vl[vrow * PADK + vpart * 8] =
          *(const s16x8*)&Vh[(size_t)vrow * TT + kv + vpart * 8];
    }
    __syncthreads();

    f32x4 s[2];
    #pragma unroll
    for (int kt = 0; kt < 2; ++kt) {
      f32x4 a = {0.f, 0.f, 0.f, 0.f};
      #pragma unroll
      for (int ds = 0; ds < 2; ++ds) {
        s16x8 kf = *(const s16x8*)&Kl[(kt * 16 + c) * 72 + ds * 32 + g * 8];
        a = __builtin_amdgcn_mfma_f32_16x16x32_bf16(qf[ds], kf, a, 0, 0, 0);
      }
      s[kt] = a;
    }
    // causal mask (scale already folded into Q)
    #pragma unroll
    for (int kt = 0; kt < 2; ++kt)
      #pragma unroll
      for (int r = 0; r < 4; ++r)
        if (kv + kt * 16 + c > qrow + r) s[kt][r] = -INFINITY;

    float tmax[4], mnew[4], alpha[4], rsum[4];
    #pragma unroll
    for (int r = 0; r < 4; ++r) tmax[r] = fmaxf(s[0][r], s[1][r]);
    #pragma unroll
    for (int off = 1; off <= 8; off <<= 1)
      #pragma unroll
      for (int r = 0; r < 4; ++r) tmax[r] = fmaxf(tmax[r], __shfl_xor(tmax[r], off));
    ushort pb[2][4];
    #pragma unroll
    for (int r = 0; r < 4; ++r) {
      mnew[r] = fmaxf(mrun[r], tmax[r]);
      alpha[r] = __expf(mrun[r] - mnew[r]);  // exp(-inf)=0 on first tile
      rsum[r] = 0.f;
    }
    #pragma unroll
    for (int kt = 0; kt < 2; ++kt)
      #pragma unroll
      for (int r = 0; r < 4; ++r) {
        float p = __expf(s[kt][r] - mnew[r]);
        rsum[r] += p;
        pb[kt][r] = f2b(p);
      }
    #pragma unroll
    for (int off = 1; off <= 8; off <<= 1)
      #pragma unroll
      for (int r = 0; r < 4; ++r) rsum[r] += __shfl_xor(rsum[r], off);
    #pragma unroll
    for (int r = 0; r < 4; ++r) {
      lrun[r] = lrun[r] * alpha[r] + rsum[r];
      mrun[r] = mnew[r];
    }
    #pragma unroll
    for (int dt = 0; dt < 4; ++dt)
      #pragma unroll
      for (int r = 0; r < 4; ++r) ctx[dt][r] *= alpha[r];

    // P (bf16) -> per-wave LDS, re-layout D->A-frag
    ushort* pw = &Pl[w][0];
    #pragma unroll
    for (int kt = 0; kt < 2; ++kt)
      #pragma unroll
      for (int r = 0; r < 4; ++r) pw[(g * 4 + r) * PADK + kt * 16 + c] = pb[kt][r];
    asm volatile("s_waitcnt lgkmcnt(0)" ::: "memory");
    s16x8 pf = *(const s16x8*)&pw[c * PADK + g * 8];
    #pragma unroll
    for (int dt = 0; dt < 4; ++dt) {
      s16x8 vf = *(const s16x8*)&Vl[(dt * 16 + c) * PADK + g * 8];
      ctx[dt] = __builtin_amdgcn_mfma_f32_16x16x32_bf16(pf, vf, ctx[dt], 0, 0, 0);
    }
  }

  int b = bh >> 4, h = bh & 15;
  ushort* dst = &Ctx[((size_t)(b * TT) + qrow) * DIN + h * HD];
  #pragma unroll
  for (int r = 0; r < 4; ++r) {
    float inv = 1.f / lrun[r];
    #pragma unroll
    for (int dt = 0; dt < 4; ++dt)
      dst[(size_t)r * DIN + dt * 16 + c] = f2b(ctx[dt][r] * inv);
  }
}

// ---------- output projection + bias (fp32 out) ----------
__global__ __launch_bounds__(256) void gemm_out(const ushort* __restrict__ Cb,
                                                const ushort* __restrict__ Wot,
                                                const float* __restrict__ bo,
                                                float* __restrict__ Out) {
  __shared__ ushort Al[128 * PADK];
  __shared__ ushort Bl[128 * PADK];
  int tid = threadIdx.x, lane = tid & 63, wid = tid >> 6;
  int wr = wid >> 1, wc = wid & 1, g = lane >> 4, c = lane & 15;
  int m0 = blockIdx.y * 128, n0 = blockIdx.x * 128;
  f32x4 acc[4][4] = {};
  for (int k0 = 0; k0 < DIN; k0 += 32) {
    __syncthreads();
    #pragma unroll
    for (int j = 0; j < 2; ++j) {
      int ci = tid + j * 256;
      int row = ci >> 2, part = ci & 3;
      *(s16x8*)&Al[row * PADK + part * 8] =
          *(const s16x8*)&Cb[(size_t)(m0 + row) * DIN + k0 + part * 8];
      *(s16x8*)&Bl[row * PADK + part * 8] =
          *(const s16x8*)&Wot[(size_t)(n0 + row) * DIN + k0 + part * 8];
    }
    __syncthreads();
    s16x8 af[4], bfr[4];
    #pragma unroll
    for (int i = 0; i < 4; ++i) {
      af[i]  = *(const s16x8*)&Al[(wr * 64 + i * 16 + c) * PADK + g * 8];
      bfr[i] = *(const s16x8*)&Bl[(wc * 64 + i * 16 + c) * PADK + g * 8];
    }
    #pragma unroll
    for (int i = 0; i < 4; ++i)
      #pragma unroll
      for (int jn = 0; jn < 4; ++jn)
        acc[i][jn] = __builtin_amdgcn_mfma_f32_16x16x32_bf16(af[i], bfr[jn], acc[i][jn], 0, 0, 0);
  }
  #pragma unroll
  for (int i = 0; i < 4; ++i)
    #pragma unroll
    for (int jn = 0; jn < 4; ++jn) {
      int mrow = m0 + wr * 64 + i * 16 + g * 4;
      int n = n0 + wc * 64 + jn * 16 + c;
      float bias = bo[n];
      float* dst = &Out[(size_t)mrow * DIN + n];
      #pragma unroll
      for (int r = 0; r < 4; ++r) dst[(size_t)r * DIN] = acc[i][jn][r] + bias;
    }
}

extern "C" void kernel_launch(void* const* d_in, const int* in_sizes, int n_in,
                              void* d_out, int out_size, void* d_ws, size_t ws_size,
                              hipStream_t stream) {
  const float* x  = (const float*)d_in[0];
  const float* Wq = (const float*)d_in[1];
  const float* Wk = (const float*)d_in[2];
  const float* Wv = (const float*)d_in[3];
  const float* Wo = (const float*)d_in[4];
  const float* bo = (const float*)d_in[5];
  float* Out = (float*)d_out;

  char* ws = (char*)d_ws;
  size_t off = 0;
  auto alloc = [&](size_t bytes) -> char* {
    char* p = ws + off;
    off += (bytes + 255) & ~(size_t)255;
    return p;
  };
  ushort* Xb  = (ushort*)alloc((size_t)M_TOK * DIN * 2);      // 8 MB
  ushort* Wt3 = (ushort*)alloc((size_t)3 * 1024 * DIN * 2);   // 6 MB
  ushort* Wot = (ushort*)alloc((size_t)1024 * 1024 * 2);      // 2 MB
  ushort* Qb  = (ushort*)alloc((size_t)NB * NH * TT * HD * 2);// 8 MB
  ushort* Kb  = (ushort*)alloc((size_t)NB * NH * TT * HD * 2);// 8 MB
  ushort* Vt  = (ushort*)alloc((size_t)NB * NH * TT * HD * 2);// 8 MB
  ushort* Cb  = (ushort*)alloc((size_t)M_TOK * DIN * 2);      // 8 MB

  cvt_f32_bf16<<<(M_TOK * DIN / 8 + 255) / 256, 256, 0, stream>>>(x, Xb, M_TOK * DIN / 8);
  dim3 tgrid(1024 / 32, 1024 / 32);
  transpose_cvt<<<tgrid, 256, 0, stream>>>(Wq, Wt3,                   1024, 1024);
  transpose_cvt<<<tgrid, 256, 0, stream>>>(Wk, Wt3 + 1024 * 1024,     1024, 1024);
  transpose_cvt<<<tgrid, 256, 0, stream>>>(Wv, Wt3 + 2 * 1024 * 1024, 1024, 1024);
  transpose_cvt<<<tgrid, 256, 0, stream>>>(Wo, Wot,                   1024, 1024);

  gemm_qkv<<<dim3(3072 / 128, M_TOK / 128), 256, 0, stream>>>(Xb, Wt3, Qb, Kb, Vt);
  attn_fwd<<<dim3(TT / 64, NB * NH), 256, 0, stream>>>(Qb, Kb, Vt, Cb);
  gemm_out<<<dim3(1024 / 128, M_TOK / 128), 256, 0, stream>>>(Cb, Wot, bo, Out);
}

// Round 5
// 294.844 us; speedup vs baseline: 1.1511x; 1.1511x over previous
//
#include <hip/hip_runtime.h>
#include <hip/hip_bf16.h>
#include <math.h>

using f32x4  = __attribute__((ext_vector_type(4)))  float;
using f32x16 = __attribute__((ext_vector_type(16))) float;
using s16x8  = __attribute__((ext_vector_type(8)))  short;
using s16x4  = __attribute__((ext_vector_type(4)))  short;

#define HD 64
#define NH 16
#define TT 2048
#define DIN 1024
#define NB 2
#define M_TOK (NB*TT)   // 4096
#define PADK 40         // 32-elem K-slab padded to 40 (80B rows, 16B aligned)
#define PSTR 36         // P LDS row stride (ushorts): 72B rows -> <=2-way bank conflict

__device__ __forceinline__ ushort f2b(float f) {
  union { float f; unsigned u; } v; v.f = f;
  unsigned u = v.u;
  return (ushort)((u + 0x7FFFu + ((u >> 16) & 1u)) >> 16);  // RNE
}

// ---------- conversions ----------
__global__ __launch_bounds__(256) void cvt_f32_bf16(const float* __restrict__ in,
                                                    ushort* __restrict__ out, int n8) {
  int i = blockIdx.x * 256 + threadIdx.x;
  if (i >= n8) return;
  const f32x4* p = (const f32x4*)(in + (size_t)i * 8);
  f32x4 a = p[0], b = p[1];
  s16x8 o;
  o[0]=(short)f2b(a[0]); o[1]=(short)f2b(a[1]); o[2]=(short)f2b(a[2]); o[3]=(short)f2b(a[3]);
  o[4]=(short)f2b(b[0]); o[5]=(short)f2b(b[1]); o[6]=(short)f2b(b[2]); o[7]=(short)f2b(b[3]);
  *(s16x8*)(out + (size_t)i * 8) = o;
}

// Wt[n][k] = W[k][n], bf16
__global__ __launch_bounds__(256) void transpose_cvt(const float* __restrict__ W,
                                                     ushort* __restrict__ Wt, int K, int N) {
  __shared__ float tile[32][33];
  int nb = blockIdx.x * 32, kb = blockIdx.y * 32;
  int tx = threadIdx.x & 31, ty = threadIdx.x >> 5;  // 32 x 8
  #pragma unroll
  for (int j = ty; j < 32; j += 8) tile[j][tx] = W[(size_t)(kb + j) * N + nb + tx];
  __syncthreads();
  #pragma unroll
  for (int j = ty; j < 32; j += 8) Wt[(size_t)(nb + j) * K + kb + tx] = f2b(tile[tx][j]);
}

// ---------- fused QKV projection GEMM ----------
__global__ __launch_bounds__(256) void gemm_qkv(const ushort* __restrict__ Xb,
                                                const ushort* __restrict__ Wt,
                                                ushort* __restrict__ Qb,
                                                ushort* __restrict__ Kb,
                                                ushort* __restrict__ Vt) {
  __shared__ ushort Al[128 * PADK];
  __shared__ ushort Bl[128 * PADK];
  int tid = threadIdx.x, lane = tid & 63, wid = tid >> 6;
  int wr = wid >> 1, wc = wid & 1, g = lane >> 4, c = lane & 15;
  int m0 = blockIdx.y * 128, n0 = blockIdx.x * 128;
  f32x4 acc[4][4] = {};
  for (int k0 = 0; k0 < DIN; k0 += 32) {
    __syncthreads();
    #pragma unroll
    for (int j = 0; j < 2; ++j) {
      int ci = tid + j * 256;
      int row = ci >> 2, part = ci & 3;
      *(s16x8*)&Al[row * PADK + part * 8] =
          *(const s16x8*)&Xb[(size_t)(m0 + row) * DIN + k0 + part * 8];
      *(s16x8*)&Bl[row * PADK + part * 8] =
          *(const s16x8*)&Wt[(size_t)(n0 + row) * DIN + k0 + part * 8];
    }
    __syncthreads();
    s16x8 af[4], bfr[4];
    #pragma unroll
    for (int i = 0; i < 4; ++i) {
      af[i]  = *(const s16x8*)&Al[(wr * 64 + i * 16 + c) * PADK + g * 8];
      bfr[i] = *(const s16x8*)&Bl[(wc * 64 + i * 16 + c) * PADK + g * 8];
    }
    #pragma unroll
    for (int i = 0; i < 4; ++i)
      #pragma unroll
      for (int jn = 0; jn < 4; ++jn)
        acc[i][jn] = __builtin_amdgcn_mfma_f32_16x16x32_bf16(af[i], bfr[jn], acc[i][jn], 0, 0, 0);
  }
  #pragma unroll
  for (int i = 0; i < 4; ++i)
    #pragma unroll
    for (int jn = 0; jn < 4; ++jn) {
      int mrow = m0 + wr * 64 + i * 16 + g * 4;
      int n = n0 + wc * 64 + jn * 16 + c;
      int b = mrow >> 11, t = mrow & (TT - 1);
      int which = n >> 10, nn = n & 1023, h = nn >> 6, d = nn & 63;
      size_t bh = (size_t)(b * NH + h);
      if (which == 2) {                              // V -> Vt[b][h][d][t]
        s16x4 pk;
        pk[0]=(short)f2b(acc[i][jn][0]); pk[1]=(short)f2b(acc[i][jn][1]);
        pk[2]=(short)f2b(acc[i][jn][2]); pk[3]=(short)f2b(acc[i][jn][3]);
        *(s16x4*)&Vt[(bh * HD + d) * TT + t] = pk;
      } else {
        float sc = (which == 0) ? 0.125f : 1.0f;     // fold softmax scale into Q
        ushort* dst = (which == 0) ? &Qb[(bh * TT + t) * HD + d]
                                   : &Kb[(bh * TT + t) * HD + d];
        #pragma unroll
        for (int r = 0; r < 4; ++r) dst[(size_t)r * HD] = f2b(acc[i][jn][r] * sc);
      }
    }
}

// ---------- causal flash attention, barrier-free swapped-operand 32x32 ----------
// grid: (T/128, B*H); block 256 = 4 independent waves, each owns 32 q-rows.
// S^T = mfma(A=K, B=Q)  -> q in lane dim, kv in reg dim  (softmax lane-local)
// ctx^T = mfma(A=V^T, B=P^T) -> q stays in lane dim (rescale = scalar mul)
__global__ __launch_bounds__(256) void attn_fwd(const ushort* __restrict__ Qb,
                                                const ushort* __restrict__ Kb,
                                                const ushort* __restrict__ Vt,
                                                ushort* __restrict__ Ctx) {
  __shared__ ushort Pl[4][32 * PSTR];   // per-wave P tile: [q=32][kv=32] stride 36
  int bh = blockIdx.y;
  int qchunk = (gridDim.x - 1) - blockIdx.x;        // long blocks first
  int q0 = qchunk * 128;
  const ushort* Qh = Qb + (size_t)bh * TT * HD;
  const ushort* Kh = Kb + (size_t)bh * TT * HD;
  const ushort* Vh = Vt + (size_t)bh * HD * TT;
  int tid = threadIdx.x, lane = tid & 63, w = tid >> 6;
  int hi = lane >> 5, c32 = lane & 31;
  int qw = q0 + w * 32;
  int q_abs = qw + c32;

  // Q resident in registers: qf[s] = Q[q_abs][s*16 + 8*hi .. +7]
  s16x8 qf[4];
  #pragma unroll
  for (int s = 0; s < 4; ++s)
    qf[s] = *(const s16x8*)&Qh[(size_t)q_abs * HD + s * 16 + 8 * hi];

  f32x16 cA[2] = {};          // ctx^T: d = (r&3)+8*(r>>2)+4*hi + 32*dt, q = c32
  float m = -INFINITY, l = 0.f;
  ushort* pw = &Pl[w][0];
  int nt = qw / 32 + 1;

  for (int t = 0; t < nt; ++t) {
    int kv0 = t * 32;
    // ---- QK^T (swapped): S^T[kv][q] ----
    f32x16 S = {};
    #pragma unroll
    for (int s = 0; s < 4; ++s) {
      s16x8 kf = *(const s16x8*)&Kh[(size_t)(kv0 + c32) * HD + s * 16 + 8 * hi];
      S = __builtin_amdgcn_mfma_f32_32x32x16_bf16(kf, qf[s], S, 0, 0, 0);
    }
    // ---- causal mask: kv in reg dim ----
    #pragma unroll
    for (int r = 0; r < 16; ++r) {
      int kv_abs = kv0 + (r & 3) + 8 * (r >> 2) + 4 * hi;
      S[r] = (kv_abs > q_abs) ? -INFINITY : S[r];
    }
    // ---- online softmax (lane-local; one cross-half shuffle per reduce) ----
    float tmax = S[0];
    #pragma unroll
    for (int r = 1; r < 16; ++r) tmax = fmaxf(tmax, S[r]);
    tmax = fmaxf(tmax, __shfl_xor(tmax, 32));
    float mnew = fmaxf(m, tmax);
    float alpha = __expf(m - mnew);
    float p[16], rsum = 0.f;
    #pragma unroll
    for (int r = 0; r < 16; ++r) { p[r] = __expf(S[r] - mnew); rsum += p[r]; }
    rsum += __shfl_xor(rsum, 32);
    l = l * alpha + rsum;
    m = mnew;
    #pragma unroll
    for (int dt = 0; dt < 2; ++dt)
      #pragma unroll
      for (int r = 0; r < 16; ++r) cA[dt][r] *= alpha;
    // ---- P^T -> wave-private LDS as P[q][kv] (bf16 pairs, kv even) ----
    #pragma unroll
    for (int j = 0; j < 8; ++j) {
      int kvb = ((2 * j) & 3) + 8 * (j >> 1) + 4 * hi;   // 0,2,8,10,16,18,24,26 (+4*hi)
      unsigned word = (unsigned)f2b(p[2 * j]) | ((unsigned)f2b(p[2 * j + 1]) << 16);
      *(unsigned*)&pw[c32 * PSTR + kvb] = word;
    }
    asm volatile("s_waitcnt lgkmcnt(0)" ::: "memory");  // same-wave DS write->read fence
    // ---- PV (swapped): ctx^T += V^T-slice * P^T-slice ----
    #pragma unroll
    for (int ks = 0; ks < 2; ++ks) {
      s16x8 pf = *(const s16x8*)&pw[c32 * PSTR + ks * 16 + 8 * hi];
      #pragma unroll
      for (int dt = 0; dt < 2; ++dt) {
        s16x8 vf = *(const s16x8*)&Vh[(size_t)(dt * 32 + c32) * TT + kv0 + ks * 16 + 8 * hi];
        cA[dt] = __builtin_amdgcn_mfma_f32_32x32x16_bf16(vf, pf, cA[dt], 0, 0, 0);
      }
    }
  }

  // ---- epilogue: ctx^T/l -> Ctx[b][t][h*64+d] bf16 ----
  int b = bh >> 4, h = bh & 15;
  float inv = 1.f / l;
  ushort* dst = &Ctx[((size_t)(b * TT) + q_abs) * DIN + h * HD];
  #pragma unroll
  for (int dt = 0; dt < 2; ++dt)
    #pragma unroll
    for (int g4 = 0; g4 < 4; ++g4) {
      int dbase = 8 * g4 + 4 * hi + 32 * dt;
      s16x4 pk;
      #pragma unroll
      for (int rr = 0; rr < 4; ++rr) pk[rr] = (short)f2b(cA[dt][g4 * 4 + rr] * inv);
      *(s16x4*)&dst[dbase] = pk;
    }
}

// ---------- output projection + bias (fp32 out) ----------
__global__ __launch_bounds__(256) void gemm_out(const ushort* __restrict__ Cb,
                                                const ushort* __restrict__ Wot,
                                                const float* __restrict__ bo,
                                                float* __restrict__ Out) {
  __shared__ ushort Al[128 * PADK];
  __shared__ ushort Bl[128 * PADK];
  int tid = threadIdx.x, lane = tid & 63, wid = tid >> 6;
  int wr = wid >> 1, wc = wid & 1, g = lane >> 4, c = lane & 15;
  int m0 = blockIdx.y * 128, n0 = blockIdx.x * 128;
  f32x4 acc[4][4] = {};
  for (int k0 = 0; k0 < DIN; k0 += 32) {
    __syncthreads();
    #pragma unroll
    for (int j = 0; j < 2; ++j) {
      int ci = tid + j * 256;
      int row = ci >> 2, part = ci & 3;
      *(s16x8*)&Al[row * PADK + part * 8] =
          *(const s16x8*)&Cb[(size_t)(m0 + row) * DIN + k0 + part * 8];
      *(s16x8*)&Bl[row * PADK + part * 8] =
          *(const s16x8*)&Wot[(size_t)(n0 + row) * DIN + k0 + part * 8];
    }
    __syncthreads();
    s16x8 af[4], bfr[4];
    #pragma unroll
    for (int i = 0; i < 4; ++i) {
      af[i]  = *(const s16x8*)&Al[(wr * 64 + i * 16 + c) * PADK + g * 8];
      bfr[i] = *(const s16x8*)&Bl[(wc * 64 + i * 16 + c) * PADK + g * 8];
    }
    #pragma unroll
    for (int i = 0; i < 4; ++i)
      #pragma unroll
      for (int jn = 0; jn < 4; ++jn)
        acc[i][jn] = __builtin_amdgcn_mfma_f32_16x16x32_bf16(af[i], bfr[jn], acc[i][jn], 0, 0, 0);
  }
  #pragma unroll
  for (int i = 0; i < 4; ++i)
    #pragma unroll
    for (int jn = 0; jn < 4; ++jn) {
      int mrow = m0 + wr * 64 + i * 16 + g * 4;
      int n = n0 + wc * 64 + jn * 16 + c;
      float bias = bo[n];
      float* dst = &Out[(size_t)mrow * DIN + n];
      #pragma unroll
      for (int r = 0; r < 4; ++r) dst[(size_t)r * DIN] = acc[i][jn][r] + bias;
    }
}

extern "C" void kernel_launch(void* const* d_in, const int* in_sizes, int n_in,
                              void* d_out, int out_size, void* d_ws, size_t ws_size,
                              hipStream_t stream) {
  const float* x  = (const float*)d_in[0];
  const float* Wq = (const float*)d_in[1];
  const float* Wk = (const float*)d_in[2];
  const float* Wv = (const float*)d_in[3];
  const float* Wo = (const float*)d_in[4];
  const float* bo = (const float*)d_in[5];
  float* Out = (float*)d_out;

  char* ws = (char*)d_ws;
  size_t off = 0;
  auto alloc = [&](size_t bytes) -> char* {
    char* p = ws + off;
    off += (bytes + 255) & ~(size_t)255;
    return p;
  };
  ushort* Xb  = (ushort*)alloc((size_t)M_TOK * DIN * 2);
  ushort* Wt3 = (ushort*)alloc((size_t)3 * 1024 * DIN * 2);
  ushort* Wot = (ushort*)alloc((size_t)1024 * 1024 * 2);
  ushort* Qb  = (ushort*)alloc((size_t)NB * NH * TT * HD * 2);
  ushort* Kb  = (ushort*)alloc((size_t)NB * NH * TT * HD * 2);
  ushort* Vt  = (ushort*)alloc((size_t)NB * NH * TT * HD * 2);
  ushort* Cb  = (ushort*)alloc((size_t)M_TOK * DIN * 2);

  cvt_f32_bf16<<<(M_TOK * DIN / 8 + 255) / 256, 256, 0, stream>>>(x, Xb, M_TOK * DIN / 8);
  dim3 tgrid(1024 / 32, 1024 / 32);
  transpose_cvt<<<tgrid, 256, 0, stream>>>(Wq, Wt3,                   1024, 1024);
  transpose_cvt<<<tgrid, 256, 0, stream>>>(Wk, Wt3 + 1024 * 1024,     1024, 1024);
  transpose_cvt<<<tgrid, 256, 0, stream>>>(Wv, Wt3 + 2 * 1024 * 1024, 1024, 1024);
  transpose_cvt<<<tgrid, 256, 0, stream>>>(Wo, Wot,                   1024, 1024);

  gemm_qkv<<<dim3(3072 / 128, M_TOK / 128), 256, 0, stream>>>(Xb, Wt3, Qb, Kb, Vt);
  attn_fwd<<<dim3(TT / 128, NB * NH), 256, 0, stream>>>(Qb, Kb, Vt, Cb);
  gemm_out<<<dim3(1024 / 128, M_TOK / 128), 256, 0, stream>>>(Cb, Wot, bo, Out);
}

// Round 6
// 275.367 us; speedup vs baseline: 1.2325x; 1.0707x over previous
//
#include <hip/hip_runtime.h>
#include <hip/hip_bf16.h>
#include <math.h>

using f32x4  = __attribute__((ext_vector_type(4)))  float;
using f32x16 = __attribute__((ext_vector_type(16))) float;
using s16x8  = __attribute__((ext_vector_type(8)))  short;
using s16x4  = __attribute__((ext_vector_type(4)))  short;

#define HD 64
#define NH 16
#define TT 2048
#define DIN 1024
#define NB 2
#define M_TOK (NB*TT)   // 4096
#define PADK 40         // 32-elem K-slab padded to 40 (80B rows, 16B aligned)
#define PSTR 36         // P LDS row stride (ushorts)

__device__ __forceinline__ ushort f2b(float f) {
  union { float f; unsigned u; } v; v.f = f;
  unsigned u = v.u;
  return (ushort)((u + 0x7FFFu + ((u >> 16) & 1u)) >> 16);  // RNE
}

// ---------- conversions ----------
__global__ __launch_bounds__(256) void cvt_f32_bf16(const float* __restrict__ in,
                                                    ushort* __restrict__ out, int n8) {
  int i = blockIdx.x * 256 + threadIdx.x;
  if (i >= n8) return;
  const f32x4* p = (const f32x4*)(in + (size_t)i * 8);
  f32x4 a = p[0], b = p[1];
  s16x8 o;
  o[0]=(short)f2b(a[0]); o[1]=(short)f2b(a[1]); o[2]=(short)f2b(a[2]); o[3]=(short)f2b(a[3]);
  o[4]=(short)f2b(b[0]); o[5]=(short)f2b(b[1]); o[6]=(short)f2b(b[2]); o[7]=(short)f2b(b[3]);
  *(s16x8*)(out + (size_t)i * 8) = o;
}

// Wt[n][k] = W[k][n], bf16
__global__ __launch_bounds__(256) void transpose_cvt(const float* __restrict__ W,
                                                     ushort* __restrict__ Wt, int K, int N) {
  __shared__ float tile[32][33];
  int nb = blockIdx.x * 32, kb = blockIdx.y * 32;
  int tx = threadIdx.x & 31, ty = threadIdx.x >> 5;  // 32 x 8
  #pragma unroll
  for (int j = ty; j < 32; j += 8) tile[j][tx] = W[(size_t)(kb + j) * N + nb + tx];
  __syncthreads();
  #pragma unroll
  for (int j = ty; j < 32; j += 8) Wt[(size_t)(nb + j) * K + kb + tx] = f2b(tile[tx][j]);
}

// ---------- fused QKV projection GEMM ----------
__global__ __launch_bounds__(256) void gemm_qkv(const ushort* __restrict__ Xb,
                                                const ushort* __restrict__ Wt,
                                                ushort* __restrict__ Qb,
                                                ushort* __restrict__ Kb,
                                                ushort* __restrict__ Vt) {
  __shared__ ushort Al[128 * PADK];
  __shared__ ushort Bl[128 * PADK];
  int tid = threadIdx.x, lane = tid & 63, wid = tid >> 6;
  int wr = wid >> 1, wc = wid & 1, g = lane >> 4, c = lane & 15;
  int m0 = blockIdx.y * 128, n0 = blockIdx.x * 128;
  f32x4 acc[4][4] = {};
  for (int k0 = 0; k0 < DIN; k0 += 32) {
    __syncthreads();
    #pragma unroll
    for (int j = 0; j < 2; ++j) {
      int ci = tid + j * 256;
      int row = ci >> 2, part = ci & 3;
      *(s16x8*)&Al[row * PADK + part * 8] =
          *(const s16x8*)&Xb[(size_t)(m0 + row) * DIN + k0 + part * 8];
      *(s16x8*)&Bl[row * PADK + part * 8] =
          *(const s16x8*)&Wt[(size_t)(n0 + row) * DIN + k0 + part * 8];
    }
    __syncthreads();
    s16x8 af[4], bfr[4];
    #pragma unroll
    for (int i = 0; i < 4; ++i) {
      af[i]  = *(const s16x8*)&Al[(wr * 64 + i * 16 + c) * PADK + g * 8];
      bfr[i] = *(const s16x8*)&Bl[(wc * 64 + i * 16 + c) * PADK + g * 8];
    }
    #pragma unroll
    for (int i = 0; i < 4; ++i)
      #pragma unroll
      for (int jn = 0; jn < 4; ++jn)
        acc[i][jn] = __builtin_amdgcn_mfma_f32_16x16x32_bf16(af[i], bfr[jn], acc[i][jn], 0, 0, 0);
  }
  #pragma unroll
  for (int i = 0; i < 4; ++i)
    #pragma unroll
    for (int jn = 0; jn < 4; ++jn) {
      int mrow = m0 + wr * 64 + i * 16 + g * 4;
      int n = n0 + wc * 64 + jn * 16 + c;
      int b = mrow >> 11, t = mrow & (TT - 1);
      int which = n >> 10, nn = n & 1023, h = nn >> 6, d = nn & 63;
      size_t bh = (size_t)(b * NH + h);
      if (which == 2) {                              // V -> Vt[b][h][d][t]
        s16x4 pk;
        pk[0]=(short)f2b(acc[i][jn][0]); pk[1]=(short)f2b(acc[i][jn][1]);
        pk[2]=(short)f2b(acc[i][jn][2]); pk[3]=(short)f2b(acc[i][jn][3]);
        *(s16x4*)&Vt[(bh * HD + d) * TT + t] = pk;
      } else {
        // Q: fold softmax scale AND log2(e) (base-2 softmax downstream)
        float sc = (which == 0) ? 0.125f * 1.44269504f : 1.0f;
        ushort* dst = (which == 0) ? &Qb[(bh * TT + t) * HD + d]
                                   : &Kb[(bh * TT + t) * HD + d];
        #pragma unroll
        for (int r = 0; r < 4; ++r) dst[(size_t)r * HD] = f2b(acc[i][jn][r] * sc);
      }
    }
}

// ---------- causal flash attention: split-KV across 4 waves of a block ----------
// grid: (T/32, B*H); block 256 = 4 waves. Block owns 32 q-rows; wave w handles
// kv tiles t = w, w+4, ... with private (m,l,ctx^T); flash-combine via LDS.
// S^T = mfma(A=K, B=Q); ctx^T = mfma(A=V^T, B=P^T): q stays in lane dim.
__global__ __launch_bounds__(256) void attn_fwd(const ushort* __restrict__ Qb,
                                                const ushort* __restrict__ Kb,
                                                const ushort* __restrict__ Vt,
                                                ushort* __restrict__ Ctx) {
  // phase 1: first 4*32*PSTR ushorts = per-wave P tiles (9216 B)
  // phase 2 (after barrier): ctxb[4][32][68] f32 (34816 B) + mbuf/lbuf (1024 B)
  __shared__ __align__(16) char smem[35840];
  int bh = blockIdx.y;
  int qc = (gridDim.x - 1) - blockIdx.x;            // long blocks first
  int q0 = qc * 32;
  const ushort* Qh = Qb + (size_t)bh * TT * HD;
  const ushort* Kh = Kb + (size_t)bh * TT * HD;
  const ushort* Vh = Vt + (size_t)bh * HD * TT;
  int tid = threadIdx.x, lane = tid & 63, w = tid >> 6;
  int hi = lane >> 5, c32 = lane & 31;
  int q_abs = q0 + c32;
  int nt = qc + 1;                                  // causal: tiles 0..nt-1

  ushort* pw = (ushort*)smem + w * (32 * PSTR);

  // Q resident in registers: qf[s] = Q[q_abs][s*16 + 8*hi .. +7]
  s16x8 qf[4];
  #pragma unroll
  for (int s = 0; s < 4; ++s)
    qf[s] = *(const s16x8*)&Qh[(size_t)q_abs * HD + s * 16 + 8 * hi];

  f32x16 cA[2] = {};          // ctx^T: d = (r&3)+8*(r>>2)+4*hi + 32*dt, q = c32
  float m = -INFINITY, l = 0.f;

  // K prefetch for this wave's first tile
  s16x8 kfc[4];
  {
    int tt = (w < nt) ? w : 0;
    #pragma unroll
    for (int s = 0; s < 4; ++s)
      kfc[s] = *(const s16x8*)&Kh[(size_t)(tt * 32 + c32) * HD + s * 16 + 8 * hi];
  }

  for (int t = w; t < nt; t += 4) {
    int kv0 = t * 32;
    // prefetch next tile's K (clamped to current on last iteration)
    int tn = (t + 4 < nt) ? (t + 4) : t;
    s16x8 kfn[4];
    #pragma unroll
    for (int s = 0; s < 4; ++s)
      kfn[s] = *(const s16x8*)&Kh[(size_t)(tn * 32 + c32) * HD + s * 16 + 8 * hi];

    // ---- QK^T (swapped): S^T[kv][q], base-2 units ----
    f32x16 S = {};
    #pragma unroll
    for (int s = 0; s < 4; ++s)
      S = __builtin_amdgcn_mfma_f32_32x32x16_bf16(kfc[s], qf[s], S, 0, 0, 0);
    // ---- causal mask: kv in reg dim ----
    #pragma unroll
    for (int r = 0; r < 16; ++r) {
      int kv_abs = kv0 + (r & 3) + 8 * (r >> 2) + 4 * hi;
      S[r] = (kv_abs > q_abs) ? -INFINITY : S[r];
    }
    // ---- online softmax (lane-local, tree reduce, one cross-half shuffle) ----
    float mx[8];
    #pragma unroll
    for (int i = 0; i < 8; ++i) mx[i] = fmaxf(S[2 * i], S[2 * i + 1]);
    #pragma unroll
    for (int i = 0; i < 4; ++i) mx[i] = fmaxf(mx[i], mx[i + 4]);
    mx[0] = fmaxf(fmaxf(mx[0], mx[2]), fmaxf(mx[1], mx[3]));
    float tmax = fmaxf(mx[0], __shfl_xor(mx[0], 32));
    float mnew = fmaxf(m, tmax);
    float alpha = exp2f(m - mnew);
    float p[16];
    #pragma unroll
    for (int r = 0; r < 16; ++r) p[r] = exp2f(S[r] - mnew);
    float sm[8];
    #pragma unroll
    for (int i = 0; i < 8; ++i) sm[i] = p[2 * i] + p[2 * i + 1];
    #pragma unroll
    for (int i = 0; i < 4; ++i) sm[i] += sm[i + 4];
    float rsum = (sm[0] + sm[2]) + (sm[1] + sm[3]);
    rsum += __shfl_xor(rsum, 32);
    l = l * alpha + rsum;
    m = mnew;
    #pragma unroll
    for (int dt = 0; dt < 2; ++dt)
      #pragma unroll
      for (int r = 0; r < 16; ++r) cA[dt][r] *= alpha;
    // ---- P^T -> wave-private LDS as P[q][kv] (bf16 pairs, kv even) ----
    #pragma unroll
    for (int j = 0; j < 8; ++j) {
      int kvb = ((2 * j) & 3) + 8 * (j >> 1) + 4 * hi;
      unsigned word = (unsigned)f2b(p[2 * j]) | ((unsigned)f2b(p[2 * j + 1]) << 16);
      *(unsigned*)&pw[c32 * PSTR + kvb] = word;
    }
    asm volatile("s_waitcnt lgkmcnt(0)" ::: "memory");  // same-wave DS write->read fence
    // ---- PV (swapped): ctx^T += V^T-slice * P^T-slice ----
    #pragma unroll
    for (int ks = 0; ks < 2; ++ks) {
      s16x8 vf0 = *(const s16x8*)&Vh[(size_t)(0 * 32 + c32) * TT + kv0 + ks * 16 + 8 * hi];
      s16x8 vf1 = *(const s16x8*)&Vh[(size_t)(1 * 32 + c32) * TT + kv0 + ks * 16 + 8 * hi];
      s16x8 pf  = *(const s16x8*)&pw[c32 * PSTR + ks * 16 + 8 * hi];
      cA[0] = __builtin_amdgcn_mfma_f32_32x32x16_bf16(vf0, pf, cA[0], 0, 0, 0);
      cA[1] = __builtin_amdgcn_mfma_f32_32x32x16_bf16(vf1, pf, cA[1], 0, 0, 0);
    }
    #pragma unroll
    for (int s = 0; s < 4; ++s) kfc[s] = kfn[s];
  }

  // ---- flash-combine across the 4 waves ----
  __syncthreads();                       // all P-tile usage done; smem repurposed
  float* ctxb = (float*)smem;            // [4][32][68]
  float* mbuf = (float*)(smem + 34816);  // [4][32]
  float* lbuf = mbuf + 128;              // [4][32]
  #pragma unroll
  for (int dt = 0; dt < 2; ++dt)
    #pragma unroll
    for (int g4 = 0; g4 < 4; ++g4) {
      f32x4 v = { cA[dt][g4 * 4 + 0], cA[dt][g4 * 4 + 1],
                  cA[dt][g4 * 4 + 2], cA[dt][g4 * 4 + 3] };
      *(f32x4*)&ctxb[(size_t)(w * 32 + c32) * 68 + 32 * dt + 8 * g4 + 4 * hi] = v;
    }
  if (!hi) { mbuf[w * 32 + c32] = m; lbuf[w * 32 + c32] = l; }
  __syncthreads();

  // reduce: thread handles (q = tid>>3, d = (tid&7)*8 .. +7)
  int q = tid >> 3, dg = tid & 7;
  float mw[4];
  #pragma unroll
  for (int ww = 0; ww < 4; ++ww) mw[ww] = mbuf[ww * 32 + q];
  float mG = fmaxf(fmaxf(mw[0], mw[1]), fmaxf(mw[2], mw[3]));
  float lt = 0.f;
  f32x4 a0 = {0.f, 0.f, 0.f, 0.f}, a1 = {0.f, 0.f, 0.f, 0.f};
  #pragma unroll
  for (int ww = 0; ww < 4; ++ww) {
    float e = exp2f(mw[ww] - mG);
    lt += e * lbuf[ww * 32 + q];
    const float* src = &ctxb[(size_t)(ww * 32 + q) * 68 + dg * 8];
    f32x4 u0 = *(const f32x4*)&src[0];
    f32x4 u1 = *(const f32x4*)&src[4];
    #pragma unroll
    for (int j = 0; j < 4; ++j) { a0[j] += e * u0[j]; a1[j] += e * u1[j]; }
  }
  float inv = 1.f / lt;
  int b = bh >> 4, h = bh & 15;
  ushort* dst = &Ctx[((size_t)(b * TT) + q0 + q) * DIN + h * HD + dg * 8];
  s16x8 o;
  #pragma unroll
  for (int j = 0; j < 4; ++j) {
    o[j]     = (short)f2b(a0[j] * inv);
    o[4 + j] = (short)f2b(a1[j] * inv);
  }
  *(s16x8*)dst = o;
}

// ---------- output projection + bias (fp32 out) ----------
__global__ __launch_bounds__(256) void gemm_out(const ushort* __restrict__ Cb,
                                                const ushort* __restrict__ Wot,
                                                const float* __restrict__ bo,
                                                float* __restrict__ Out) {
  __shared__ ushort Al[128 * PADK];
  __shared__ ushort Bl[128 * PADK];
  int tid = threadIdx.x, lane = tid & 63, wid = tid >> 6;
  int wr = wid >> 1, wc = wid & 1, g = lane >> 4, c = lane & 15;
  int m0 = blockIdx.y * 128, n0 = blockIdx.x * 128;
  f32x4 acc[4][4] = {};
  for (int k0 = 0; k0 < DIN; k0 += 32) {
    __syncthreads();
    #pragma unroll
    for (int j = 0; j < 2; ++j) {
      int ci = tid + j * 256;
      int row = ci >> 2, part = ci & 3;
      *(s16x8*)&Al[row * PADK + part * 8] =
          *(const s16x8*)&Cb[(size_t)(m0 + row) * DIN + k0 + part * 8];
      *(s16x8*)&Bl[row * PADK + part * 8] =
          *(const s16x8*)&Wot[(size_t)(n0 + row) * DIN + k0 + part * 8];
    }
    __syncthreads();
    s16x8 af[4], bfr[4];
    #pragma unroll
    for (int i = 0; i < 4; ++i) {
      af[i]  = *(const s16x8*)&Al[(wr * 64 + i * 16 + c) * PADK + g * 8];
      bfr[i] = *(const s16x8*)&Bl[(wc * 64 + i * 16 + c) * PADK + g * 8];
    }
    #pragma unroll
    for (int i = 0; i < 4; ++i)
      #pragma unroll
      for (int jn = 0; jn < 4; ++jn)
        acc[i][jn] = __builtin_amdgcn_mfma_f32_16x16x32_bf16(af[i], bfr[jn], acc[i][jn], 0, 0, 0);
  }
  #pragma unroll
  for (int i = 0; i < 4; ++i)
    #pragma unroll
    for (int jn = 0; jn < 4; ++jn) {
      int mrow = m0 + wr * 64 + i * 16 + g * 4;
      int n = n0 + wc * 64 + jn * 16 + c;
      float bias = bo[n];
      float* dst = &Out[(size_t)mrow * DIN + n];
      #pragma unroll
      for (int r = 0; r < 4; ++r) dst[(size_t)r * DIN] = acc[i][jn][r] + bias;
    }
}

extern "C" void kernel_launch(void* const* d_in, const int* in_sizes, int n_in,
                              void* d_out, int out_size, void* d_ws, size_t ws_size,
                              hipStream_t stream) {
  const float* x  = (const float*)d_in[0];
  const float* Wq = (const float*)d_in[1];
  const float* Wk = (const float*)d_in[2];
  const float* Wv = (const float*)d_in[3];
  const float* Wo = (const float*)d_in[4];
  const float* bo = (const float*)d_in[5];
  float* Out = (float*)d_out;

  char* ws = (char*)d_ws;
  size_t off = 0;
  auto alloc = [&](size_t bytes) -> char* {
    char* p = ws + off;
    off += (bytes + 255) & ~(size_t)255;
    return p;
  };
  ushort* Xb  = (ushort*)alloc((size_t)M_TOK * DIN * 2);
  ushort* Wt3 = (ushort*)alloc((size_t)3 * 1024 * DIN * 2);
  ushort* Wot = (ushort*)alloc((size_t)1024 * 1024 * 2);
  ushort* Qb  = (ushort*)alloc((size_t)NB * NH * TT * HD * 2);
  ushort* Kb  = (ushort*)alloc((size_t)NB * NH * TT * HD * 2);
  ushort* Vt  = (ushort*)alloc((size_t)NB * NH * TT * HD * 2);
  ushort* Cb  = (ushort*)alloc((size_t)M_TOK * DIN * 2);

  cvt_f32_bf16<<<(M_TOK * DIN / 8 + 255) / 256, 256, 0, stream>>>(x, Xb, M_TOK * DIN / 8);
  dim3 tgrid(1024 / 32, 1024 / 32);
  transpose_cvt<<<tgrid, 256, 0, stream>>>(Wq, Wt3,                   1024, 1024);
  transpose_cvt<<<tgrid, 256, 0, stream>>>(Wk, Wt3 + 1024 * 1024,     1024, 1024);
  transpose_cvt<<<tgrid, 256, 0, stream>>>(Wv, Wt3 + 2 * 1024 * 1024, 1024, 1024);
  transpose_cvt<<<tgrid, 256, 0, stream>>>(Wo, Wot,                   1024, 1024);

  gemm_qkv<<<dim3(3072 / 128, M_TOK / 128), 256, 0, stream>>>(Xb, Wt3, Qb, Kb, Vt);
  attn_fwd<<<dim3(TT / 32, NB * NH), 256, 0, stream>>>(Qb, Kb, Vt, Cb);
  gemm_out<<<dim3(1024 / 128, M_TOK / 128), 256, 0, stream>>>(Cb, Wot, bo, Out);
}

// Round 7
// 275.195 us; speedup vs baseline: 1.2333x; 1.0006x over previous
//
#include <hip/hip_runtime.h>
#include <hip/hip_bf16.h>
#include <math.h>

using f32x4  = __attribute__((ext_vector_type(4)))  float;
using f32x16 = __attribute__((ext_vector_type(16))) float;
using s16x8  = __attribute__((ext_vector_type(8)))  short;
using s16x4  = __attribute__((ext_vector_type(4)))  short;

#define HD 64
#define NH 16
#define TT 2048
#define DIN 1024
#define NB 2
#define M_TOK (NB*TT)   // 4096
#define PADK 40         // GEMM LDS row stride
#define PSTR 36         // P LDS row stride (ushorts)

__device__ __forceinline__ ushort f2b(float f) {
  union { float f; unsigned u; } v; v.f = f;
  unsigned u = v.u;
  return (ushort)((u + 0x7FFFu + ((u >> 16) & 1u)) >> 16);  // RNE
}

// two f32 -> packed bf16x2 (RNE), single HW instr on gfx950
__device__ __forceinline__ unsigned cvt_pk_bf16(float lo, float hi) {
  unsigned r;
  asm("v_cvt_pk_bf16_f32 %0, %1, %2" : "=v"(r) : "v"(lo), "v"(hi));
  return r;
}

// ---------- conversions ----------
__global__ __launch_bounds__(256) void cvt_f32_bf16(const float* __restrict__ in,
                                                    ushort* __restrict__ out, int n8) {
  int i = blockIdx.x * 256 + threadIdx.x;
  if (i >= n8) return;
  const f32x4* p = (const f32x4*)(in + (size_t)i * 8);
  f32x4 a = p[0], b = p[1];
  s16x8 o;
  o[0]=(short)f2b(a[0]); o[1]=(short)f2b(a[1]); o[2]=(short)f2b(a[2]); o[3]=(short)f2b(a[3]);
  o[4]=(short)f2b(b[0]); o[5]=(short)f2b(b[1]); o[6]=(short)f2b(b[2]); o[7]=(short)f2b(b[3]);
  *(s16x8*)(out + (size_t)i * 8) = o;
}

// Wt[n][k] = W[k][n], bf16
__global__ __launch_bounds__(256) void transpose_cvt(const float* __restrict__ W,
                                                     ushort* __restrict__ Wt, int K, int N) {
  __shared__ float tile[32][33];
  int nb = blockIdx.x * 32, kb = blockIdx.y * 32;
  int tx = threadIdx.x & 31, ty = threadIdx.x >> 5;  // 32 x 8
  #pragma unroll
  for (int j = ty; j < 32; j += 8) tile[j][tx] = W[(size_t)(kb + j) * N + nb + tx];
  __syncthreads();
  #pragma unroll
  for (int j = ty; j < 32; j += 8) Wt[(size_t)(nb + j) * K + kb + tx] = f2b(tile[tx][j]);
}

// ---------- fused QKV projection GEMM ----------
__global__ __launch_bounds__(256) void gemm_qkv(const ushort* __restrict__ Xb,
                                                const ushort* __restrict__ Wt,
                                                ushort* __restrict__ Qb,
                                                ushort* __restrict__ Kb,
                                                ushort* __restrict__ Vt) {
  __shared__ ushort Al[128 * PADK];
  __shared__ ushort Bl[128 * PADK];
  int tid = threadIdx.x, lane = tid & 63, wid = tid >> 6;
  int wr = wid >> 1, wc = wid & 1, g = lane >> 4, c = lane & 15;
  int m0 = blockIdx.y * 128, n0 = blockIdx.x * 128;
  f32x4 acc[4][4] = {};
  for (int k0 = 0; k0 < DIN; k0 += 32) {
    __syncthreads();
    #pragma unroll
    for (int j = 0; j < 2; ++j) {
      int ci = tid + j * 256;
      int row = ci >> 2, part = ci & 3;
      *(s16x8*)&Al[row * PADK + part * 8] =
          *(const s16x8*)&Xb[(size_t)(m0 + row) * DIN + k0 + part * 8];
      *(s16x8*)&Bl[row * PADK + part * 8] =
          *(const s16x8*)&Wt[(size_t)(n0 + row) * DIN + k0 + part * 8];
    }
    __syncthreads();
    s16x8 af[4], bfr[4];
    #pragma unroll
    for (int i = 0; i < 4; ++i) {
      af[i]  = *(const s16x8*)&Al[(wr * 64 + i * 16 + c) * PADK + g * 8];
      bfr[i] = *(const s16x8*)&Bl[(wc * 64 + i * 16 + c) * PADK + g * 8];
    }
    #pragma unroll
    for (int i = 0; i < 4; ++i)
      #pragma unroll
      for (int jn = 0; jn < 4; ++jn)
        acc[i][jn] = __builtin_amdgcn_mfma_f32_16x16x32_bf16(af[i], bfr[jn], acc[i][jn], 0, 0, 0);
  }
  #pragma unroll
  for (int i = 0; i < 4; ++i)
    #pragma unroll
    for (int jn = 0; jn < 4; ++jn) {
      int mrow = m0 + wr * 64 + i * 16 + g * 4;
      int n = n0 + wc * 64 + jn * 16 + c;
      int b = mrow >> 11, t = mrow & (TT - 1);
      int which = n >> 10, nn = n & 1023, h = nn >> 6, d = nn & 63;
      size_t bh = (size_t)(b * NH + h);
      if (which == 2) {                              // V -> Vt[b][h][d][t]
        s16x4 pk;
        pk[0]=(short)f2b(acc[i][jn][0]); pk[1]=(short)f2b(acc[i][jn][1]);
        pk[2]=(short)f2b(acc[i][jn][2]); pk[3]=(short)f2b(acc[i][jn][3]);
        *(s16x4*)&Vt[(bh * HD + d) * TT + t] = pk;
      } else {
        // Q: fold softmax scale AND log2(e) (base-2 softmax downstream)
        float sc = (which == 0) ? 0.125f * 1.44269504f : 1.0f;
        ushort* dst = (which == 0) ? &Qb[(bh * TT + t) * HD + d]
                                   : &Kb[(bh * TT + t) * HD + d];
        #pragma unroll
        for (int r = 0; r < 4; ++r) dst[(size_t)r * HD] = f2b(acc[i][jn][r] * sc);
      }
    }
}

// ---------- causal flash attention: split-KV, low-LDS, prefetched ----------
// grid: (T/32, B*H); block 256 = 4 waves. Block owns 32 q-rows; wave w handles
// kv tiles t = w, w+4, ...; flash-combine via 4-round LDS reduce (11 KB total).
__global__ __launch_bounds__(256, 4) void attn_fwd(const ushort* __restrict__ Qb,
                                                   const ushort* __restrict__ Kb,
                                                   const ushort* __restrict__ Vt,
                                                   ushort* __restrict__ Ctx) {
  // [0,9216): per-wave P tiles [4][32][PSTR] ushort
  // combine phase reuses [0,10240): cb[4][32][20] f32 ; mb/lb at [10240,11264)
  __shared__ __align__(16) char smem[11264];
  int bh = blockIdx.y;
  int qc = (gridDim.x - 1) - blockIdx.x;            // long blocks first
  int q0 = qc * 32;
  const ushort* Qh = Qb + (size_t)bh * TT * HD;
  const ushort* Kh = Kb + (size_t)bh * TT * HD;
  const ushort* Vh = Vt + (size_t)bh * HD * TT;
  int tid = threadIdx.x, lane = tid & 63, w = tid >> 6;
  int hi = lane >> 5, c32 = lane & 31;
  int q_abs = q0 + c32;
  int nt = qc + 1;                                  // causal tile count

  ushort* pw = (ushort*)smem + w * (32 * PSTR);

  // Q resident: qf[s] = Q[q_abs][s*16 + 8*hi .. +7]
  s16x8 qf[4];
  #pragma unroll
  for (int s = 0; s < 4; ++s)
    qf[s] = *(const s16x8*)&Qh[(size_t)q_abs * HD + s * 16 + 8 * hi];

  f32x16 cA[2] = {};          // ctx^T: d = (r&3)+8*(r>>2)+4*hi + 32*dt, q = c32
  float m = -INFINITY, l = 0.f;

  // K frags for this wave's first tile
  s16x8 kfc[4];
  {
    int tt = (w < nt) ? w : 0;
    #pragma unroll
    for (int s = 0; s < 4; ++s)
      kfc[s] = *(const s16x8*)&Kh[(size_t)(tt * 32 + c32) * HD + s * 16 + 8 * hi];
  }

  for (int t = w; t < nt; t += 4) {
    int kv0 = t * 32;
    // ---- V for current tile, hoisted (overlaps QK + softmax) ----
    s16x8 vf0[2], vf1[2];
    #pragma unroll
    for (int ks = 0; ks < 2; ++ks) {
      vf0[ks] = *(const s16x8*)&Vh[(size_t)c32 * TT + kv0 + ks * 16 + 8 * hi];
      vf1[ks] = *(const s16x8*)&Vh[(size_t)(32 + c32) * TT + kv0 + ks * 16 + 8 * hi];
    }
    // ---- QK^T (swapped): S^T[kv][q], base-2 units ----
    f32x16 S = {};
    #pragma unroll
    for (int s = 0; s < 4; ++s)
      S = __builtin_amdgcn_mfma_f32_32x32x16_bf16(kfc[s], qf[s], S, 0, 0, 0);
    // ---- K prefetch for tile t+4 into same regs (overlaps softmax+PV) ----
    if (t + 4 < nt) {
      #pragma unroll
      for (int s = 0; s < 4; ++s)
        kfc[s] = *(const s16x8*)&Kh[(size_t)((t + 4) * 32 + c32) * HD + s * 16 + 8 * hi];
    }
    // ---- causal mask: only the diagonal tile needs it (uniform branch) ----
    if (t == qc) {
      #pragma unroll
      for (int r = 0; r < 16; ++r) {
        int pat = (r & 3) + 8 * (r >> 2) + 4 * hi;   // kv_local
        S[r] = (pat > c32) ? -INFINITY : S[r];
      }
    }
    // ---- online softmax: lane-local tree + one cross-half shuffle ----
    float mx[8];
    #pragma unroll
    for (int i = 0; i < 8; ++i) mx[i] = fmaxf(S[2 * i], S[2 * i + 1]);
    #pragma unroll
    for (int i = 0; i < 4; ++i) mx[i] = fmaxf(mx[i], mx[i + 4]);
    mx[0] = fmaxf(fmaxf(mx[0], mx[2]), fmaxf(mx[1], mx[3]));
    float tmax = fmaxf(mx[0], __shfl_xor(mx[0], 32));
    // defer-max (T13): rescale only when the running max grows by > 8 (2^8 headroom)
    if (__any(tmax > m + 8.f)) {
      float mnew = fmaxf(m, tmax);
      float alpha = exp2f(m - mnew);
      l *= alpha;
      #pragma unroll
      for (int dt = 0; dt < 2; ++dt)
        #pragma unroll
        for (int r = 0; r < 16; ++r) cA[dt][r] *= alpha;
      m = mnew;
    }
    #pragma unroll
    for (int r = 0; r < 16; ++r) S[r] = exp2f(S[r] - m);
    float sm[8];
    #pragma unroll
    for (int i = 0; i < 8; ++i) sm[i] = S[2 * i] + S[2 * i + 1];
    #pragma unroll
    for (int i = 0; i < 4; ++i) sm[i] += sm[i + 4];
    float rsum = (sm[0] + sm[2]) + (sm[1] + sm[3]);
    rsum += __shfl_xor(rsum, 32);
    l += rsum;
    // ---- P^T -> wave-private LDS (packed bf16 via cvt_pk) ----
    #pragma unroll
    for (int j = 0; j < 8; ++j) {
      int kvb = ((2 * j) & 3) + 8 * (j >> 1) + 4 * hi;
      *(unsigned*)&pw[c32 * PSTR + kvb] = cvt_pk_bf16(S[2 * j], S[2 * j + 1]);
    }
    asm volatile("s_waitcnt lgkmcnt(0)" ::: "memory");  // DS write->read fence
    // ---- PV (swapped): ctx^T += V^T-slice * P^T-slice ----
    #pragma unroll
    for (int ks = 0; ks < 2; ++ks) {
      s16x8 pf = *(const s16x8*)&pw[c32 * PSTR + ks * 16 + 8 * hi];
      cA[0] = __builtin_amdgcn_mfma_f32_32x32x16_bf16(vf0[ks], pf, cA[0], 0, 0, 0);
      cA[1] = __builtin_amdgcn_mfma_f32_32x32x16_bf16(vf1[ks], pf, cA[1], 0, 0, 0);
    }
  }

  // ---- flash-combine across the 4 waves: 4 rounds through 10 KB LDS ----
  __syncthreads();                         // all P usage done; smem repurposed
  float* cb = (float*)smem;                // [4][32][20]
  float* mb = (float*)(smem + 10240);      // [4][32]
  float* lb = mb + 128;                    // [4][32]
  if (!hi) { mb[w * 32 + c32] = m; lb[w * 32 + c32] = l; }
  __syncthreads();

  int q  = tid >> 3;                       // reducer coords: q 0..31
  int dp = (tid & 7) * 2;                  // d-pair 0..14
  float ew[4];
  {
    float mw[4];
    #pragma unroll
    for (int ww = 0; ww < 4; ++ww) mw[ww] = mb[ww * 32 + q];
    float mG = fmaxf(fmaxf(mw[0], mw[1]), fmaxf(mw[2], mw[3]));
    float lt = 0.f;
    #pragma unroll
    for (int ww = 0; ww < 4; ++ww) {
      ew[ww] = exp2f(mw[ww] - mG);
      lt += ew[ww] * lb[ww * 32 + q];
    }
    float inv = 1.f / lt;
    #pragma unroll
    for (int ww = 0; ww < 4; ++ww) ew[ww] *= inv;
  }
  int b = bh >> 4, h = bh & 15;
  #pragma unroll
  for (int rd = 0; rd < 4; ++rd) {
    int dt = rd >> 1, rh = rd & 1;
    // write my two f32x4 of this round
    float* dstq = &cb[(size_t)(w * 32 + c32) * 20];
    f32x4 v0 = { cA[dt][rh * 8 + 0], cA[dt][rh * 8 + 1], cA[dt][rh * 8 + 2], cA[dt][rh * 8 + 3] };
    f32x4 v1 = { cA[dt][rh * 8 + 4], cA[dt][rh * 8 + 5], cA[dt][rh * 8 + 6], cA[dt][rh * 8 + 7] };
    *(f32x4*)&dstq[4 * hi]     = v0;
    *(f32x4*)&dstq[8 + 4 * hi] = v1;
    __syncthreads();
    // reduce 4 waves for my (q, dp..dp+1) and store
    float s0 = 0.f, s1 = 0.f;
    #pragma unroll
    for (int ww = 0; ww < 4; ++ww) {
      const float* src = &cb[(size_t)(ww * 32 + q) * 20 + dp];
      s0 += ew[ww] * src[0];
      s1 += ew[ww] * src[1];
    }
    int dcol = h * HD + 32 * dt + 16 * rh + dp;
    *(unsigned*)&Ctx[((size_t)(b * TT) + q0 + q) * DIN + dcol] = cvt_pk_bf16(s0, s1);
    if (rd < 3) __syncthreads();
  }
}

// ---------- output projection + bias (fp32 out) ----------
__global__ __launch_bounds__(256) void gemm_out(const ushort* __restrict__ Cb,
                                                const ushort* __restrict__ Wot,
                                                const float* __restrict__ bo,
                                                float* __restrict__ Out) {
  __shared__ ushort Al[128 * PADK];
  __shared__ ushort Bl[128 * PADK];
  int tid = threadIdx.x, lane = tid & 63, wid = tid >> 6;
  int wr = wid >> 1, wc = wid & 1, g = lane >> 4, c = lane & 15;
  int m0 = blockIdx.y * 128, n0 = blockIdx.x * 128;
  f32x4 acc[4][4] = {};
  for (int k0 = 0; k0 < DIN; k0 += 32) {
    __syncthreads();
    #pragma unroll
    for (int j = 0; j < 2; ++j) {
      int ci = tid + j * 256;
      int row = ci >> 2, part = ci & 3;
      *(s16x8*)&Al[row * PADK + part * 8] =
          *(const s16x8*)&Cb[(size_t)(m0 + row) * DIN + k0 + part * 8];
      *(s16x8*)&Bl[row * PADK + part * 8] =
          *(const s16x8*)&Wot[(size_t)(n0 + row) * DIN + k0 + part * 8];
    }
    __syncthreads();
    s16x8 af[4], bfr[4];
    #pragma unroll
    for (int i = 0; i < 4; ++i) {
      af[i]  = *(const s16x8*)&Al[(wr * 64 + i * 16 + c) * PADK + g * 8];
      bfr[i] = *(const s16x8*)&Bl[(wc * 64 + i * 16 + c) * PADK + g * 8];
    }
    #pragma unroll
    for (int i = 0; i < 4; ++i)
      #pragma unroll
      for (int jn = 0; jn < 4; ++jn)
        acc[i][jn] = __builtin_amdgcn_mfma_f32_16x16x32_bf16(af[i], bfr[jn], acc[i][jn], 0, 0, 0);
  }
  #pragma unroll
  for (int i = 0; i < 4; ++i)
    #pragma unroll
    for (int jn = 0; jn < 4; ++jn) {
      int mrow = m0 + wr * 64 + i * 16 + g * 4;
      int n = n0 + wc * 64 + jn * 16 + c;
      float bias = bo[n];
      float* dst = &Out[(size_t)mrow * DIN + n];
      #pragma unroll
      for (int r = 0; r < 4; ++r) dst[(size_t)r * DIN] = acc[i][jn][r] + bias;
    }
}

extern "C" void kernel_launch(void* const* d_in, const int* in_sizes, int n_in,
                              void* d_out, int out_size, void* d_ws, size_t ws_size,
                              hipStream_t stream) {
  const float* x  = (const float*)d_in[0];
  const float* Wq = (const float*)d_in[1];
  const float* Wk = (const float*)d_in[2];
  const float* Wv = (const float*)d_in[3];
  const float* Wo = (const float*)d_in[4];
  const float* bo = (const float*)d_in[5];
  float* Out = (float*)d_out;

  char* ws = (char*)d_ws;
  size_t off = 0;
  auto alloc = [&](size_t bytes) -> char* {
    char* p = ws + off;
    off += (bytes + 255) & ~(size_t)255;
    return p;
  };
  ushort* Xb  = (ushort*)alloc((size_t)M_TOK * DIN * 2);
  ushort* Wt3 = (ushort*)alloc((size_t)3 * 1024 * DIN * 2);
  ushort* Wot = (ushort*)alloc((size_t)1024 * 1024 * 2);
  ushort* Qb  = (ushort*)alloc((size_t)NB * NH * TT * HD * 2);
  ushort* Kb  = (ushort*)alloc((size_t)NB * NH * TT * HD * 2);
  ushort* Vt  = (ushort*)alloc((size_t)NB * NH * TT * HD * 2);
  ushort* Cb  = (ushort*)alloc((size_t)M_TOK * DIN * 2);

  cvt_f32_bf16<<<(M_TOK * DIN / 8 + 255) / 256, 256, 0, stream>>>(x, Xb, M_TOK * DIN / 8);
  dim3 tgrid(1024 / 32, 1024 / 32);
  transpose_cvt<<<tgrid, 256, 0, stream>>>(Wq, Wt3,                   1024, 1024);
  transpose_cvt<<<tgrid, 256, 0, stream>>>(Wk, Wt3 + 1024 * 1024,     1024, 1024);
  transpose_cvt<<<tgrid, 256, 0, stream>>>(Wv, Wt3 + 2 * 1024 * 1024, 1024, 1024);
  transpose_cvt<<<tgrid, 256, 0, stream>>>(Wo, Wot,                   1024, 1024);

  gemm_qkv<<<dim3(3072 / 128, M_TOK / 128), 256, 0, stream>>>(Xb, Wt3, Qb, Kb, Vt);
  attn_fwd<<<dim3(TT / 32, NB * NH), 256, 0, stream>>>(Qb, Kb, Vt, Cb);
  gemm_out<<<dim3(1024 / 128, M_TOK / 128), 256, 0, stream>>>(Cb, Wot, bo, Out);
}

// Round 8
// 238.535 us; speedup vs baseline: 1.4228x; 1.1537x over previous
//
#include <hip/hip_runtime.h>
#include <hip/hip_bf16.h>
#include <math.h>

using f32x4  = __attribute__((ext_vector_type(4)))  float;
using f32x16 = __attribute__((ext_vector_type(16))) float;
using s16x8  = __attribute__((ext_vector_type(8)))  short;
using s16x4  = __attribute__((ext_vector_type(4)))  short;
using u32x2  = __attribute__((ext_vector_type(2)))  unsigned;

#define HD 64
#define NH 16
#define TT 2048
#define DIN 1024
#define NB 2
#define M_TOK (NB*TT)   // 4096
#define PADK 40         // GEMM LDS row stride
#define PSTR2 68        // attn P LDS row stride (ushorts), 64 kv + 4 pad

__device__ __forceinline__ ushort f2b(float f) {
  union { float f; unsigned u; } v; v.f = f;
  unsigned u = v.u;
  return (ushort)((u + 0x7FFFu + ((u >> 16) & 1u)) >> 16);  // RNE
}

// two f32 -> packed bf16x2 (RNE), single HW instr on gfx950
__device__ __forceinline__ unsigned cvt_pk_bf16(float lo, float hi) {
  unsigned r;
  asm("v_cvt_pk_bf16_f32 %0, %1, %2" : "=v"(r) : "v"(lo), "v"(hi));
  return r;
}

// cross-half (lane ^ 32) reduce via permlane32_swap: the two outputs together
// always contain {self, partner} per lane under any half-swap semantics.
__device__ __forceinline__ float xhalf_max(float v) {
  u32x2 r = __builtin_amdgcn_permlane32_swap(__float_as_uint(v), __float_as_uint(v), false, false);
  return fmaxf(__uint_as_float(r.x), __uint_as_float(r.y));
}
__device__ __forceinline__ float xhalf_sum(float v) {
  u32x2 r = __builtin_amdgcn_permlane32_swap(__float_as_uint(v), __float_as_uint(v), false, false);
  return __uint_as_float(r.x) + __uint_as_float(r.y);
}

// ---------- conversions ----------
__global__ __launch_bounds__(256) void cvt_f32_bf16(const float* __restrict__ in,
                                                    ushort* __restrict__ out, int n8) {
  int i = blockIdx.x * 256 + threadIdx.x;
  if (i >= n8) return;
  const f32x4* p = (const f32x4*)(in + (size_t)i * 8);
  f32x4 a = p[0], b = p[1];
  s16x8 o;
  o[0]=(short)f2b(a[0]); o[1]=(short)f2b(a[1]); o[2]=(short)f2b(a[2]); o[3]=(short)f2b(a[3]);
  o[4]=(short)f2b(b[0]); o[5]=(short)f2b(b[1]); o[6]=(short)f2b(b[2]); o[7]=(short)f2b(b[3]);
  *(s16x8*)(out + (size_t)i * 8) = o;
}

// Wt[n][k] = W[k][n], bf16
__global__ __launch_bounds__(256) void transpose_cvt(const float* __restrict__ W,
                                                     ushort* __restrict__ Wt, int K, int N) {
  __shared__ float tile[32][33];
  int nb = blockIdx.x * 32, kb = blockIdx.y * 32;
  int tx = threadIdx.x & 31, ty = threadIdx.x >> 5;  // 32 x 8
  #pragma unroll
  for (int j = ty; j < 32; j += 8) tile[j][tx] = W[(size_t)(kb + j) * N + nb + tx];
  __syncthreads();
  #pragma unroll
  for (int j = ty; j < 32; j += 8) Wt[(size_t)(nb + j) * K + kb + tx] = f2b(tile[tx][j]);
}

// ---------- fused QKV projection GEMM ----------
__global__ __launch_bounds__(256) void gemm_qkv(const ushort* __restrict__ Xb,
                                                const ushort* __restrict__ Wt,
                                                ushort* __restrict__ Qb,
                                                ushort* __restrict__ Kb,
                                                ushort* __restrict__ Vt) {
  __shared__ ushort Al[128 * PADK];
  __shared__ ushort Bl[128 * PADK];
  int tid = threadIdx.x, lane = tid & 63, wid = tid >> 6;
  int wr = wid >> 1, wc = wid & 1, g = lane >> 4, c = lane & 15;
  int m0 = blockIdx.y * 128, n0 = blockIdx.x * 128;
  f32x4 acc[4][4] = {};
  for (int k0 = 0; k0 < DIN; k0 += 32) {
    __syncthreads();
    #pragma unroll
    for (int j = 0; j < 2; ++j) {
      int ci = tid + j * 256;
      int row = ci >> 2, part = ci & 3;
      *(s16x8*)&Al[row * PADK + part * 8] =
          *(const s16x8*)&Xb[(size_t)(m0 + row) * DIN + k0 + part * 8];
      *(s16x8*)&Bl[row * PADK + part * 8] =
          *(const s16x8*)&Wt[(size_t)(n0 + row) * DIN + k0 + part * 8];
    }
    __syncthreads();
    s16x8 af[4], bfr[4];
    #pragma unroll
    for (int i = 0; i < 4; ++i) {
      af[i]  = *(const s16x8*)&Al[(wr * 64 + i * 16 + c) * PADK + g * 8];
      bfr[i] = *(const s16x8*)&Bl[(wc * 64 + i * 16 + c) * PADK + g * 8];
    }
    #pragma unroll
    for (int i = 0; i < 4; ++i)
      #pragma unroll
      for (int jn = 0; jn < 4; ++jn)
        acc[i][jn] = __builtin_amdgcn_mfma_f32_16x16x32_bf16(af[i], bfr[jn], acc[i][jn], 0, 0, 0);
  }
  #pragma unroll
  for (int i = 0; i < 4; ++i)
    #pragma unroll
    for (int jn = 0; jn < 4; ++jn) {
      int mrow = m0 + wr * 64 + i * 16 + g * 4;
      int n = n0 + wc * 64 + jn * 16 + c;
      int b = mrow >> 11, t = mrow & (TT - 1);
      int which = n >> 10, nn = n & 1023, h = nn >> 6, d = nn & 63;
      size_t bh = (size_t)(b * NH + h);
      if (which == 2) {                              // V -> Vt[b][h][d][t]
        s16x4 pk;
        pk[0]=(short)f2b(acc[i][jn][0]); pk[1]=(short)f2b(acc[i][jn][1]);
        pk[2]=(short)f2b(acc[i][jn][2]); pk[3]=(short)f2b(acc[i][jn][3]);
        *(s16x4*)&Vt[(bh * HD + d) * TT + t] = pk;
      } else {
        // Q: fold softmax scale AND log2(e) (base-2 softmax downstream)
        float sc = (which == 0) ? 0.125f * 1.44269504f : 1.0f;
        ushort* dst = (which == 0) ? &Qb[(bh * TT + t) * HD + d]
                                   : &Kb[(bh * TT + t) * HD + d];
        #pragma unroll
        for (int r = 0; r < 4; ++r) dst[(size_t)r * HD] = f2b(acc[i][jn][r] * sc);
      }
    }
}

// ---------- causal flash attention: split-KV, KVBLK=64, XCD bh-locality ----------
// grid: 2048 blocks (flat), 256 threads = 4 waves. Decode: xcd = blk&7 serves
// heads {xcd, xcd+8, xcd+16, xcd+24} only -> per-XCD K/V working set ~= L2.
// Block owns 32 q-rows; wave w handles 64-wide kv tiles t = w, w+4, ...
__global__ __launch_bounds__(256, 2) void attn_fwd(const ushort* __restrict__ Qb,
                                                   const ushort* __restrict__ Kb,
                                                   const ushort* __restrict__ Vt,
                                                   ushort* __restrict__ Ctx) {
  // [0, 17408): per-wave P tiles [4][32][PSTR2] ushort
  // combine reuses: cb[4][32][20] f32 at [0,10240); mb/lb at [10240,11264)
  __shared__ __align__(16) char smem[17920];
  int L = blockIdx.x;
  int xcd = L & 7, j = L >> 3;
  int bh = xcd + 8 * (j & 3);
  int qc = 63 - (j >> 2);                            // long blocks first
  int q0 = qc * 32;
  const ushort* Qh = Qb + (size_t)bh * TT * HD;
  const ushort* Kh = Kb + (size_t)bh * TT * HD;
  const ushort* Vh = Vt + (size_t)bh * HD * TT;
  int tid = threadIdx.x, lane = tid & 63, w = tid >> 6;
  int hi = lane >> 5, c32 = lane & 31;
  int q_abs = q0 + c32;
  int nt64 = (q0 + 32 + 63) >> 6;                    // 64-wide kv tiles

  ushort* pw = (ushort*)smem + w * (32 * PSTR2);

  // Q resident: qf[s] = Q[q_abs][s*16 + 8*hi .. +7]
  s16x8 qf[4];
  #pragma unroll
  for (int s = 0; s < 4; ++s)
    qf[s] = *(const s16x8*)&Qh[(size_t)q_abs * HD + s * 16 + 8 * hi];

  f32x16 cA[2] = {};          // ctx^T: d = (r&3)+8*(r>>2)+4*hi + 32*dt, q = c32
  float m = -INFINITY, l = 0.f;

  // K frags for this wave's first tile (8 x 16B; ss-major)
  s16x8 kfc[8];
  {
    int tt = (w < nt64) ? w : 0;
    #pragma unroll
    for (int ss = 0; ss < 2; ++ss)
      #pragma unroll
      for (int s = 0; s < 4; ++s)
        kfc[ss * 4 + s] =
            *(const s16x8*)&Kh[(size_t)(tt * 64 + ss * 32 + c32) * HD + s * 16 + 8 * hi];
  }

  for (int t = w; t < nt64; t += 4) {
    int kv0 = t * 64;
    // ---- V for current tile, hoisted (overlaps QK + softmax) ----
    s16x8 vf[2][4];   // [dt][ks]
    #pragma unroll
    for (int dt = 0; dt < 2; ++dt)
      #pragma unroll
      for (int ks = 0; ks < 4; ++ks)
        vf[dt][ks] = *(const s16x8*)&Vh[(size_t)(dt * 32 + c32) * TT + kv0 + ks * 16 + 8 * hi];
    // ---- QK^T (swapped): S^T[kv][q], base-2 units; two 32-kv halves ----
    f32x16 S0 = {}, S1 = {};
    #pragma unroll
    for (int s = 0; s < 4; ++s)
      S0 = __builtin_amdgcn_mfma_f32_32x32x16_bf16(kfc[s], qf[s], S0, 0, 0, 0);
    #pragma unroll
    for (int s = 0; s < 4; ++s)
      S1 = __builtin_amdgcn_mfma_f32_32x32x16_bf16(kfc[4 + s], qf[s], S1, 0, 0, 0);
    // ---- K prefetch for tile t+4 (overlaps softmax + PV) ----
    if (t + 4 < nt64) {
      #pragma unroll
      for (int ss = 0; ss < 2; ++ss)
        #pragma unroll
        for (int s = 0; s < 4; ++s)
          kfc[ss * 4 + s] =
              *(const s16x8*)&Kh[(size_t)((t + 4) * 64 + ss * 32 + c32) * HD + s * 16 + 8 * hi];
    }
    // ---- causal mask: only tiles that touch/cross the diagonal ----
    if (kv0 + 63 > q0) {
      #pragma unroll
      for (int r = 0; r < 16; ++r) {
        int base = kv0 + (r & 3) + 8 * (r >> 2) + 4 * hi;
        S0[r] = (base > q_abs) ? -INFINITY : S0[r];
        S1[r] = (base + 32 > q_abs) ? -INFINITY : S1[r];
      }
    }
    // ---- online softmax over 32 regs (lane-local tree + permlane cross-half) ----
    float mx[8];
    #pragma unroll
    for (int i = 0; i < 8; ++i)
      mx[i] = fmaxf(fmaxf(S0[2 * i], S0[2 * i + 1]), fmaxf(S1[2 * i], S1[2 * i + 1]));
    #pragma unroll
    for (int i = 0; i < 4; ++i) mx[i] = fmaxf(mx[i], mx[i + 4]);
    mx[0] = fmaxf(fmaxf(mx[0], mx[2]), fmaxf(mx[1], mx[3]));
    float tmax = xhalf_max(mx[0]);
    // defer-max (T13): rescale only when running max grows by > 8
    if (__any(tmax > m + 8.f)) {
      float mnew = fmaxf(m, tmax);
      float alpha = exp2f(m - mnew);
      l *= alpha;
      #pragma unroll
      for (int dt = 0; dt < 2; ++dt)
        #pragma unroll
        for (int r = 0; r < 16; ++r) cA[dt][r] *= alpha;
      m = mnew;
    }
    #pragma unroll
    for (int r = 0; r < 16; ++r) { S0[r] = exp2f(S0[r] - m); S1[r] = exp2f(S1[r] - m); }
    float sm[8];
    #pragma unroll
    for (int i = 0; i < 8; ++i)
      sm[i] = (S0[2 * i] + S0[2 * i + 1]) + (S1[2 * i] + S1[2 * i + 1]);
    #pragma unroll
    for (int i = 0; i < 4; ++i) sm[i] += sm[i + 4];
    float rsum = (sm[0] + sm[2]) + (sm[1] + sm[3]);
    l += xhalf_sum(rsum);
    // ---- P^T -> wave-private LDS (packed bf16 via cvt_pk) ----
    #pragma unroll
    for (int jj = 0; jj < 8; ++jj) {
      int kvb = ((2 * jj) & 3) + 8 * (jj >> 1) + 4 * hi;
      *(unsigned*)&pw[c32 * PSTR2 + kvb]      = cvt_pk_bf16(S0[2 * jj], S0[2 * jj + 1]);
      *(unsigned*)&pw[c32 * PSTR2 + 32 + kvb] = cvt_pk_bf16(S1[2 * jj], S1[2 * jj + 1]);
    }
    asm volatile("s_waitcnt lgkmcnt(0)" ::: "memory");  // DS write->read fence
    // ---- PV (swapped): ctx^T += V^T-slice * P^T-slice, 4 k-slices ----
    #pragma unroll
    for (int ks = 0; ks < 4; ++ks) {
      s16x8 pf = *(const s16x8*)&pw[c32 * PSTR2 + ks * 16 + 8 * hi];
      cA[0] = __builtin_amdgcn_mfma_f32_32x32x16_bf16(vf[0][ks], pf, cA[0], 0, 0, 0);
      cA[1] = __builtin_amdgcn_mfma_f32_32x32x16_bf16(vf[1][ks], pf, cA[1], 0, 0, 0);
    }
  }

  // ---- flash-combine across the 4 waves: 4 rounds through 10 KB LDS ----
  __syncthreads();                         // all P usage done; smem repurposed
  float* cb = (float*)smem;                // [4][32][20]
  float* mb = (float*)(smem + 10240);      // [4][32]
  float* lb = mb + 128;                    // [4][32]
  if (!hi) { mb[w * 32 + c32] = m; lb[w * 32 + c32] = l; }
  __syncthreads();

  int q  = tid >> 3;                       // reducer coords: q 0..31
  int dp = (tid & 7) * 2;                  // d-pair 0..14
  float ew[4];
  {
    float mw[4];
    #pragma unroll
    for (int ww = 0; ww < 4; ++ww) mw[ww] = mb[ww * 32 + q];
    float mG = fmaxf(fmaxf(mw[0], mw[1]), fmaxf(mw[2], mw[3]));
    float lt = 0.f;
    #pragma unroll
    for (int ww = 0; ww < 4; ++ww) {
      ew[ww] = exp2f(mw[ww] - mG);
      lt += ew[ww] * lb[ww * 32 + q];
    }
    float inv = 1.f / lt;
    #pragma unroll
    for (int ww = 0; ww < 4; ++ww) ew[ww] *= inv;
  }
  int b = bh >> 4, h = bh & 15;
  #pragma unroll
  for (int rd = 0; rd < 4; ++rd) {
    int dt = rd >> 1, rh = rd & 1;
    float* dstq = &cb[(size_t)(w * 32 + c32) * 20];
    f32x4 v0 = { cA[dt][rh * 8 + 0], cA[dt][rh * 8 + 1], cA[dt][rh * 8 + 2], cA[dt][rh * 8 + 3] };
    f32x4 v1 = { cA[dt][rh * 8 + 4], cA[dt][rh * 8 + 5], cA[dt][rh * 8 + 6], cA[dt][rh * 8 + 7] };
    *(f32x4*)&dstq[4 * hi]     = v0;
    *(f32x4*)&dstq[8 + 4 * hi] = v1;
    __syncthreads();
    float s0 = 0.f, s1 = 0.f;
    #pragma unroll
    for (int ww = 0; ww < 4; ++ww) {
      const float* src = &cb[(size_t)(ww * 32 + q) * 20 + dp];
      s0 += ew[ww] * src[0];
      s1 += ew[ww] * src[1];
    }
    int dcol = h * HD + 32 * dt + 16 * rh + dp;
    *(unsigned*)&Ctx[((size_t)(b * TT) + q0 + q) * DIN + dcol] = cvt_pk_bf16(s0, s1);
    if (rd < 3) __syncthreads();
  }
}

// ---------- output projection + bias (fp32 out) ----------
__global__ __launch_bounds__(256) void gemm_out(const ushort* __restrict__ Cb,
                                                const ushort* __restrict__ Wot,
                                                const float* __restrict__ bo,
                                                float* __restrict__ Out) {
  __shared__ ushort Al[128 * PADK];
  __shared__ ushort Bl[128 * PADK];
  int tid = threadIdx.x, lane = tid & 63, wid = tid >> 6;
  int wr = wid >> 1, wc = wid & 1, g = lane >> 4, c = lane & 15;
  int m0 = blockIdx.y * 128, n0 = blockIdx.x * 128;
  f32x4 acc[4][4] = {};
  for (int k0 = 0; k0 < DIN; k0 += 32) {
    __syncthreads();
    #pragma unroll
    for (int j = 0; j < 2; ++j) {
      int ci = tid + j * 256;
      int row = ci >> 2, part = ci & 3;
      *(s16x8*)&Al[row * PADK + part * 8] =
          *(const s16x8*)&Cb[(size_t)(m0 + row) * DIN + k0 + part * 8];
      *(s16x8*)&Bl[row * PADK + part * 8] =
          *(const s16x8*)&Wot[(size_t)(n0 + row) * DIN + k0 + part * 8];
    }
    __syncthreads();
    s16x8 af[4], bfr[4];
    #pragma unroll
    for (int i = 0; i < 4; ++i) {
      af[i]  = *(const s16x8*)&Al[(wr * 64 + i * 16 + c) * PADK + g * 8];
      bfr[i] = *(const s16x8*)&Bl[(wc * 64 + i * 16 + c) * PADK + g * 8];
    }
    #pragma unroll
    for (int i = 0; i < 4; ++i)
      #pragma unroll
      for (int jn = 0; jn < 4; ++jn)
        acc[i][jn] = __builtin_amdgcn_mfma_f32_16x16x32_bf16(af[i], bfr[jn], acc[i][jn], 0, 0, 0);
  }
  #pragma unroll
  for (int i = 0; i < 4; ++i)
    #pragma unroll
    for (int jn = 0; jn < 4; ++jn) {
      int mrow = m0 + wr * 64 + i * 16 + g * 4;
      int n = n0 + wc * 64 + jn * 16 + c;
      float bias = bo[n];
      float* dst = &Out[(size_t)mrow * DIN + n];
      #pragma unroll
      for (int r = 0; r < 4; ++r) dst[(size_t)r * DIN] = acc[i][jn][r] + bias;
    }
}

extern "C" void kernel_launch(void* const* d_in, const int* in_sizes, int n_in,
                              void* d_out, int out_size, void* d_ws, size_t ws_size,
                              hipStream_t stream) {
  const float* x  = (const float*)d_in[0];
  const float* Wq = (const float*)d_in[1];
  const float* Wk = (const float*)d_in[2];
  const float* Wv = (const float*)d_in[3];
  const float* Wo = (const float*)d_in[4];
  const float* bo = (const float*)d_in[5];
  float* Out = (float*)d_out;

  char* ws = (char*)d_ws;
  size_t off = 0;
  auto alloc = [&](size_t bytes) -> char* {
    char* p = ws + off;
    off += (bytes + 255) & ~(size_t)255;
    return p;
  };
  ushort* Xb  = (ushort*)alloc((size_t)M_TOK * DIN * 2);
  ushort* Wt3 = (ushort*)alloc((size_t)3 * 1024 * DIN * 2);
  ushort* Wot = (ushort*)alloc((size_t)1024 * 1024 * 2);
  ushort* Qb  = (ushort*)alloc((size_t)NB * NH * TT * HD * 2);
  ushort* Kb  = (ushort*)alloc((size_t)NB * NH * TT * HD * 2);
  ushort* Vt  = (ushort*)alloc((size_t)NB * NH * TT * HD * 2);
  ushort* Cb  = (ushort*)alloc((size_t)M_TOK * DIN * 2);

  cvt_f32_bf16<<<(M_TOK * DIN / 8 + 255) / 256, 256, 0, stream>>>(x, Xb, M_TOK * DIN / 8);
  dim3 tgrid(1024 / 32, 1024 / 32);
  transpose_cvt<<<tgrid, 256, 0, stream>>>(Wq, Wt3,                   1024, 1024);
  transpose_cvt<<<tgrid, 256, 0, stream>>>(Wk, Wt3 + 1024 * 1024,     1024, 1024);
  transpose_cvt<<<tgrid, 256, 0, stream>>>(Wv, Wt3 + 2 * 1024 * 1024, 1024, 1024);
  transpose_cvt<<<tgrid, 256, 0, stream>>>(Wo, Wot,                   1024, 1024);

  gemm_qkv<<<dim3(3072 / 128, M_TOK / 128), 256, 0, stream>>>(Xb, Wt3, Qb, Kb, Vt);
  attn_fwd<<<2048, 256, 0, stream>>>(Qb, Kb, Vt, Cb);
  gemm_out<<<dim3(1024 / 128, M_TOK / 128), 256, 0, stream>>>(Cb, Wot, bo, Out);
}

// Round 9
// 227.555 us; speedup vs baseline: 1.4914x; 1.0483x over previous
//
#include <hip/hip_runtime.h>
#include <hip/hip_bf16.h>
#include <math.h>

using f32x4  = __attribute__((ext_vector_type(4)))  float;
using f32x16 = __attribute__((ext_vector_type(16))) float;
using s16x8  = __attribute__((ext_vector_type(8)))  short;
using s16x4  = __attribute__((ext_vector_type(4)))  short;
using u32x2  = __attribute__((ext_vector_type(2)))  unsigned;

#define HD 64
#define NH 16
#define TT 2048
#define DIN 1024
#define NB 2
#define M_TOK (NB*TT)   // 4096
#define PSTR2 68        // attn P LDS row stride (ushorts), 64 kv + 4 pad

__device__ __forceinline__ ushort f2b(float f) {
  union { float f; unsigned u; } v; v.f = f;
  unsigned u = v.u;
  return (ushort)((u + 0x7FFFu + ((u >> 16) & 1u)) >> 16);  // RNE
}

// two f32 -> packed bf16x2 (RNE), single HW instr on gfx950
__device__ __forceinline__ unsigned cvt_pk_bf16(float lo, float hi) {
  unsigned r;
  asm("v_cvt_pk_bf16_f32 %0, %1, %2" : "=v"(r) : "v"(lo), "v"(hi));
  return r;
}

// cross-half (lane ^ 32) reduce via permlane32_swap
__device__ __forceinline__ float xhalf_max(float v) {
  u32x2 r = __builtin_amdgcn_permlane32_swap(__float_as_uint(v), __float_as_uint(v), false, false);
  return fmaxf(__uint_as_float(r.x), __uint_as_float(r.y));
}
__device__ __forceinline__ float xhalf_sum(float v) {
  u32x2 r = __builtin_amdgcn_permlane32_swap(__float_as_uint(v), __float_as_uint(v), false, false);
  return __uint_as_float(r.x) + __uint_as_float(r.y);
}

// async global->LDS, 16B per lane; lds dest = wave-uniform base + lane*16
__device__ __forceinline__ void gll16(const ushort* g, ushort* l) {
  __builtin_amdgcn_global_load_lds(
      (const __attribute__((address_space(1))) unsigned*)g,
      (__attribute__((address_space(3))) unsigned*)l, 16, 0, 0);
}

// ---------- conversions ----------
__global__ __launch_bounds__(256) void cvt_f32_bf16(const float* __restrict__ in,
                                                    ushort* __restrict__ out, int n8) {
  int i = blockIdx.x * 256 + threadIdx.x;
  if (i >= n8) return;
  const f32x4* p = (const f32x4*)(in + (size_t)i * 8);
  f32x4 a = p[0], b = p[1];
  s16x8 o;
  o[0]=(short)f2b(a[0]); o[1]=(short)f2b(a[1]); o[2]=(short)f2b(a[2]); o[3]=(short)f2b(a[3]);
  o[4]=(short)f2b(b[0]); o[5]=(short)f2b(b[1]); o[6]=(short)f2b(b[2]); o[7]=(short)f2b(b[3]);
  *(s16x8*)(out + (size_t)i * 8) = o;
}

// All four weight transposes in one launch: Wt[n][k] = W[k][n], bf16 (1024x1024 each)
__global__ __launch_bounds__(256) void transpose_cvt4(const float* __restrict__ W0,
                                                      const float* __restrict__ W1,
                                                      const float* __restrict__ W2,
                                                      const float* __restrict__ W3,
                                                      ushort* __restrict__ Wt3,
                                                      ushort* __restrict__ Wot) {
  __shared__ float tile[32][33];
  int z = blockIdx.z;
  const float* W = (z == 0) ? W0 : (z == 1) ? W1 : (z == 2) ? W2 : W3;
  ushort* Wt = (z < 3) ? (Wt3 + (size_t)z * 1024 * 1024) : Wot;
  int nb = blockIdx.x * 32, kb = blockIdx.y * 32;
  int tx = threadIdx.x & 31, ty = threadIdx.x >> 5;  // 32 x 8
  #pragma unroll
  for (int j = ty; j < 32; j += 8) tile[j][tx] = W[(size_t)(kb + j) * 1024 + nb + tx];
  __syncthreads();
  #pragma unroll
  for (int j = ty; j < 32; j += 8) Wt[(size_t)(nb + j) * 1024 + kb + tx] = f2b(tile[tx][j]);
}

// ---------- fused QKV projection GEMM (m97 structure) ----------
// C[4096 x 3072] = Xb @ W (Wt is B^T). LDS linear [128][32], global_load_lds w=16.
__global__ __launch_bounds__(256) void gemm_qkv(const ushort* __restrict__ Xb,
                                                const ushort* __restrict__ Wt,
                                                ushort* __restrict__ Qb,
                                                ushort* __restrict__ Kb,
                                                ushort* __restrict__ Vt) {
  __shared__ ushort Al[128 * 32];
  __shared__ ushort Bl[128 * 32];
  int tid = threadIdx.x, lane = tid & 63;
  int wid = tid >> 6;
  int wr = wid >> 1, wc = wid & 1, g = lane >> 4, c = lane & 15;
  int m0 = blockIdx.y * 128, n0 = blockIdx.x * 128;
  int row1 = tid >> 2, part = tid & 3;        // chunk ci = tid
  int row2 = 64 + row1;                       // chunk ci = tid + 256
  int wbase = (tid & ~63) * 8;                // wave-uniform LDS ushort offset
  f32x4 acc[4][4] = {};
  for (int k0 = 0; k0 < DIN; k0 += 32) {
    __syncthreads();                          // prior reads done; safe to overwrite
    gll16(&Xb[(size_t)(m0 + row1) * DIN + k0 + part * 8], &Al[wbase]);
    gll16(&Xb[(size_t)(m0 + row2) * DIN + k0 + part * 8], &Al[2048 + wbase]);
    gll16(&Wt[(size_t)(n0 + row1) * DIN + k0 + part * 8], &Bl[wbase]);
    gll16(&Wt[(size_t)(n0 + row2) * DIN + k0 + part * 8], &Bl[2048 + wbase]);
    __syncthreads();                          // vmcnt(0) drained before barrier
    s16x8 af[4], bfr[4];
    #pragma unroll
    for (int i = 0; i < 4; ++i) {
      af[i]  = *(const s16x8*)&Al[(wr * 64 + i * 16 + c) * 32 + g * 8];
      bfr[i] = *(const s16x8*)&Bl[(wc * 64 + i * 16 + c) * 32 + g * 8];
    }
    #pragma unroll
    for (int i = 0; i < 4; ++i)
      #pragma unroll
      for (int jn = 0; jn < 4; ++jn)
        acc[i][jn] = __builtin_amdgcn_mfma_f32_16x16x32_bf16(af[i], bfr[jn], acc[i][jn], 0, 0, 0);
  }
  #pragma unroll
  for (int i = 0; i < 4; ++i)
    #pragma unroll
    for (int jn = 0; jn < 4; ++jn) {
      int mrow = m0 + wr * 64 + i * 16 + g * 4;
      int n = n0 + wc * 64 + jn * 16 + c;
      int b = mrow >> 11, t = mrow & (TT - 1);
      int which = n >> 10, nn = n & 1023, h = nn >> 6, d = nn & 63;
      size_t bh = (size_t)(b * NH + h);
      if (which == 2) {                              // V -> Vt[b][h][d][t]
        s16x4 pk;
        pk[0]=(short)f2b(acc[i][jn][0]); pk[1]=(short)f2b(acc[i][jn][1]);
        pk[2]=(short)f2b(acc[i][jn][2]); pk[3]=(short)f2b(acc[i][jn][3]);
        *(s16x4*)&Vt[(bh * HD + d) * TT + t] = pk;
      } else {
        // Q: fold softmax scale AND log2(e) (base-2 softmax downstream)
        float sc = (which == 0) ? 0.125f * 1.44269504f : 1.0f;
        ushort* dst = (which == 0) ? &Qb[(bh * TT + t) * HD + d]
                                   : &Kb[(bh * TT + t) * HD + d];
        #pragma unroll
        for (int r = 0; r < 4; ++r) dst[(size_t)r * HD] = f2b(acc[i][jn][r] * sc);
      }
    }
}

// ---------- causal flash attention: split-KV, KVBLK=64, XCD bh-locality ----------
__global__ __launch_bounds__(256, 2) void attn_fwd(const ushort* __restrict__ Qb,
                                                   const ushort* __restrict__ Kb,
                                                   const ushort* __restrict__ Vt,
                                                   ushort* __restrict__ Ctx) {
  __shared__ __align__(16) char smem[17920];
  int L = blockIdx.x;
  int xcd = L & 7, j = L >> 3;
  int bh = xcd + 8 * (j & 3);
  int qc = 63 - (j >> 2);                            // long blocks first
  int q0 = qc * 32;
  const ushort* Qh = Qb + (size_t)bh * TT * HD;
  const ushort* Kh = Kb + (size_t)bh * TT * HD;
  const ushort* Vh = Vt + (size_t)bh * HD * TT;
  int tid = threadIdx.x, lane = tid & 63, w = tid >> 6;
  int hi = lane >> 5, c32 = lane & 31;
  int q_abs = q0 + c32;
  int nt64 = (q0 + 32 + 63) >> 6;                    // 64-wide kv tiles

  ushort* pw = (ushort*)smem + w * (32 * PSTR2);

  s16x8 qf[4];
  #pragma unroll
  for (int s = 0; s < 4; ++s)
    qf[s] = *(const s16x8*)&Qh[(size_t)q_abs * HD + s * 16 + 8 * hi];

  f32x16 cA[2] = {};
  float m = -INFINITY, l = 0.f;

  s16x8 kfc[8];
  {
    int tt = (w < nt64) ? w : 0;
    #pragma unroll
    for (int ss = 0; ss < 2; ++ss)
      #pragma unroll
      for (int s = 0; s < 4; ++s)
        kfc[ss * 4 + s] =
            *(const s16x8*)&Kh[(size_t)(tt * 64 + ss * 32 + c32) * HD + s * 16 + 8 * hi];
  }

  for (int t = w; t < nt64; t += 4) {
    int kv0 = t * 64;
    s16x8 vf[2][4];
    #pragma unroll
    for (int dt = 0; dt < 2; ++dt)
      #pragma unroll
      for (int ks = 0; ks < 4; ++ks)
        vf[dt][ks] = *(const s16x8*)&Vh[(size_t)(dt * 32 + c32) * TT + kv0 + ks * 16 + 8 * hi];
    f32x16 S0 = {}, S1 = {};
    #pragma unroll
    for (int s = 0; s < 4; ++s)
      S0 = __builtin_amdgcn_mfma_f32_32x32x16_bf16(kfc[s], qf[s], S0, 0, 0, 0);
    #pragma unroll
    for (int s = 0; s < 4; ++s)
      S1 = __builtin_amdgcn_mfma_f32_32x32x16_bf16(kfc[4 + s], qf[s], S1, 0, 0, 0);
    if (t + 4 < nt64) {
      #pragma unroll
      for (int ss = 0; ss < 2; ++ss)
        #pragma unroll
        for (int s = 0; s < 4; ++s)
          kfc[ss * 4 + s] =
              *(const s16x8*)&Kh[(size_t)((t + 4) * 64 + ss * 32 + c32) * HD + s * 16 + 8 * hi];
    }
    if (kv0 + 63 > q0) {
      #pragma unroll
      for (int r = 0; r < 16; ++r) {
        int base = kv0 + (r & 3) + 8 * (r >> 2) + 4 * hi;
        S0[r] = (base > q_abs) ? -INFINITY : S0[r];
        S1[r] = (base + 32 > q_abs) ? -INFINITY : S1[r];
      }
    }
    float mx[8];
    #pragma unroll
    for (int i = 0; i < 8; ++i)
      mx[i] = fmaxf(fmaxf(S0[2 * i], S0[2 * i + 1]), fmaxf(S1[2 * i], S1[2 * i + 1]));
    #pragma unroll
    for (int i = 0; i < 4; ++i) mx[i] = fmaxf(mx[i], mx[i + 4]);
    mx[0] = fmaxf(fmaxf(mx[0], mx[2]), fmaxf(mx[1], mx[3]));
    float tmax = xhalf_max(mx[0]);
    if (__any(tmax > m + 8.f)) {
      float mnew = fmaxf(m, tmax);
      float alpha = exp2f(m - mnew);
      l *= alpha;
      #pragma unroll
      for (int dt = 0; dt < 2; ++dt)
        #pragma unroll
        for (int r = 0; r < 16; ++r) cA[dt][r] *= alpha;
      m = mnew;
    }
    #pragma unroll
    for (int r = 0; r < 16; ++r) { S0[r] = exp2f(S0[r] - m); S1[r] = exp2f(S1[r] - m); }
    float sm[8];
    #pragma unroll
    for (int i = 0; i < 8; ++i)
      sm[i] = (S0[2 * i] + S0[2 * i + 1]) + (S1[2 * i] + S1[2 * i + 1]);
    #pragma unroll
    for (int i = 0; i < 4; ++i) sm[i] += sm[i + 4];
    float rsum = (sm[0] + sm[2]) + (sm[1] + sm[3]);
    l += xhalf_sum(rsum);
    #pragma unroll
    for (int jj = 0; jj < 8; ++jj) {
      int kvb = ((2 * jj) & 3) + 8 * (jj >> 1) + 4 * hi;
      *(unsigned*)&pw[c32 * PSTR2 + kvb]      = cvt_pk_bf16(S0[2 * jj], S0[2 * jj + 1]);
      *(unsigned*)&pw[c32 * PSTR2 + 32 + kvb] = cvt_pk_bf16(S1[2 * jj], S1[2 * jj + 1]);
    }
    asm volatile("s_waitcnt lgkmcnt(0)" ::: "memory");
    #pragma unroll
    for (int ks = 0; ks < 4; ++ks) {
      s16x8 pf = *(const s16x8*)&pw[c32 * PSTR2 + ks * 16 + 8 * hi];
      cA[0] = __builtin_amdgcn_mfma_f32_32x32x16_bf16(vf[0][ks], pf, cA[0], 0, 0, 0);
      cA[1] = __builtin_amdgcn_mfma_f32_32x32x16_bf16(vf[1][ks], pf, cA[1], 0, 0, 0);
    }
  }

  __syncthreads();
  float* cb = (float*)smem;                // [4][32][20]
  float* mb = (float*)(smem + 10240);      // [4][32]
  float* lb = mb + 128;                    // [4][32]
  if (!hi) { mb[w * 32 + c32] = m; lb[w * 32 + c32] = l; }
  __syncthreads();

  int q  = tid >> 3;
  int dp = (tid & 7) * 2;
  float ew[4];
  {
    float mw[4];
    #pragma unroll
    for (int ww = 0; ww < 4; ++ww) mw[ww] = mb[ww * 32 + q];
    float mG = fmaxf(fmaxf(mw[0], mw[1]), fmaxf(mw[2], mw[3]));
    float lt = 0.f;
    #pragma unroll
    for (int ww = 0; ww < 4; ++ww) {
      ew[ww] = exp2f(mw[ww] - mG);
      lt += ew[ww] * lb[ww * 32 + q];
    }
    float inv = 1.f / lt;
    #pragma unroll
    for (int ww = 0; ww < 4; ++ww) ew[ww] *= inv;
  }
  int b = bh >> 4, h = bh & 15;
  #pragma unroll
  for (int rd = 0; rd < 4; ++rd) {
    int dt = rd >> 1, rh = rd & 1;
    float* dstq = &cb[(size_t)(w * 32 + c32) * 20];
    f32x4 v0 = { cA[dt][rh * 8 + 0], cA[dt][rh * 8 + 1], cA[dt][rh * 8 + 2], cA[dt][rh * 8 + 3] };
    f32x4 v1 = { cA[dt][rh * 8 + 4], cA[dt][rh * 8 + 5], cA[dt][rh * 8 + 6], cA[dt][rh * 8 + 7] };
    *(f32x4*)&dstq[4 * hi]     = v0;
    *(f32x4*)&dstq[8 + 4 * hi] = v1;
    __syncthreads();
    float s0 = 0.f, s1 = 0.f;
    #pragma unroll
    for (int ww = 0; ww < 4; ++ww) {
      const float* src = &cb[(size_t)(ww * 32 + q) * 20 + dp];
      s0 += ew[ww] * src[0];
      s1 += ew[ww] * src[1];
    }
    int dcol = h * HD + 32 * dt + 16 * rh + dp;
    *(unsigned*)&Ctx[((size_t)(b * TT) + q0 + q) * DIN + dcol] = cvt_pk_bf16(s0, s1);
    if (rd < 3) __syncthreads();
  }
}

// ---------- output projection + bias, fp32 out (m97 structure) ----------
__global__ __launch_bounds__(256) void gemm_out(const ushort* __restrict__ Cb,
                                                const ushort* __restrict__ Wot,
                                                const float* __restrict__ bo,
                                                float* __restrict__ Out) {
  __shared__ ushort Al[128 * 32];
  __shared__ ushort Bl[128 * 32];
  int tid = threadIdx.x, lane = tid & 63;
  int wid = tid >> 6;
  int wr = wid >> 1, wc = wid & 1, g = lane >> 4, c = lane & 15;
  int m0 = blockIdx.y * 128, n0 = blockIdx.x * 128;
  int row1 = tid >> 2, part = tid & 3;
  int row2 = 64 + row1;
  int wbase = (tid & ~63) * 8;
  f32x4 acc[4][4] = {};
  for (int k0 = 0; k0 < DIN; k0 += 32) {
    __syncthreads();
    gll16(&Cb[(size_t)(m0 + row1) * DIN + k0 + part * 8], &Al[wbase]);
    gll16(&Cb[(size_t)(m0 + row2) * DIN + k0 + part * 8], &Al[2048 + wbase]);
    gll16(&Wot[(size_t)(n0 + row1) * DIN + k0 + part * 8], &Bl[wbase]);
    gll16(&Wot[(size_t)(n0 + row2) * DIN + k0 + part * 8], &Bl[2048 + wbase]);
    __syncthreads();
    s16x8 af[4], bfr[4];
    #pragma unroll
    for (int i = 0; i < 4; ++i) {
      af[i]  = *(const s16x8*)&Al[(wr * 64 + i * 16 + c) * 32 + g * 8];
      bfr[i] = *(const s16x8*)&Bl[(wc * 64 + i * 16 + c) * 32 + g * 8];
    }
    #pragma unroll
    for (int i = 0; i < 4; ++i)
      #pragma unroll
      for (int jn = 0; jn < 4; ++jn)
        acc[i][jn] = __builtin_amdgcn_mfma_f32_16x16x32_bf16(af[i], bfr[jn], acc[i][jn], 0, 0, 0);
  }
  #pragma unroll
  for (int i = 0; i < 4; ++i)
    #pragma unroll
    for (int jn = 0; jn < 4; ++jn) {
      int mrow = m0 + wr * 64 + i * 16 + g * 4;
      int n = n0 + wc * 64 + jn * 16 + c;
      float bias = bo[n];
      float* dst = &Out[(size_t)mrow * DIN + n];
      #pragma unroll
      for (int r = 0; r < 4; ++r) dst[(size_t)r * DIN] = acc[i][jn][r] + bias;
    }
}

extern "C" void kernel_launch(void* const* d_in, const int* in_sizes, int n_in,
                              void* d_out, int out_size, void* d_ws, size_t ws_size,
                              hipStream_t stream) {
  const float* x  = (const float*)d_in[0];
  const float* Wq = (const float*)d_in[1];
  const float* Wk = (const float*)d_in[2];
  const float* Wv = (const float*)d_in[3];
  const float* Wo = (const float*)d_in[4];
  const float* bo = (const float*)d_in[5];
  float* Out = (float*)d_out;

  char* ws = (char*)d_ws;
  size_t off = 0;
  auto alloc = [&](size_t bytes) -> char* {
    char* p = ws + off;
    off += (bytes + 255) & ~(size_t)255;
    return p;
  };
  ushort* Xb  = (ushort*)alloc((size_t)M_TOK * DIN * 2);
  ushort* Wt3 = (ushort*)alloc((size_t)3 * 1024 * DIN * 2);
  ushort* Wot = (ushort*)alloc((size_t)1024 * 1024 * 2);
  ushort* Qb  = (ushort*)alloc((size_t)NB * NH * TT * HD * 2);
  ushort* Kb  = (ushort*)alloc((size_t)NB * NH * TT * HD * 2);
  ushort* Vt  = (ushort*)alloc((size_t)NB * NH * TT * HD * 2);
  ushort* Cb  = (ushort*)alloc((size_t)M_TOK * DIN * 2);

  cvt_f32_bf16<<<(M_TOK * DIN / 8 + 255) / 256, 256, 0, stream>>>(x, Xb, M_TOK * DIN / 8);
  transpose_cvt4<<<dim3(32, 32, 4), 256, 0, stream>>>(Wq, Wk, Wv, Wo, Wt3, Wot);

  gemm_qkv<<<dim3(3072 / 128, M_TOK / 128), 256, 0, stream>>>(Xb, Wt3, Qb, Kb, Vt);
  attn_fwd<<<2048, 256, 0, stream>>>(Qb, Kb, Vt, Cb);
  gemm_out<<<dim3(1024 / 128, M_TOK / 128), 256, 0, stream>>>(Cb, Wot, bo, Out);
}

// Round 11
// 225.263 us; speedup vs baseline: 1.5066x; 1.0102x over previous
//
#include <hip/hip_runtime.h>
#include <hip/hip_bf16.h>
#include <math.h>

using f32x4  = __attribute__((ext_vector_type(4)))  float;
using f32x16 = __attribute__((ext_vector_type(16))) float;
using s16x8  = __attribute__((ext_vector_type(8)))  short;
using s16x4  = __attribute__((ext_vector_type(4)))  short;
using u32x2  = __attribute__((ext_vector_type(2)))  unsigned;

#define HD 64
#define NH 16
#define TT 2048
#define DIN 1024
#define NB 2
#define M_TOK (NB*TT)   // 4096
#define PSTR2 68        // attn P LDS row stride (ushorts), 64 kv + 4 pad

__device__ __forceinline__ ushort f2b(float f) {
  union { float f; unsigned u; } v; v.f = f;
  unsigned u = v.u;
  return (ushort)((u + 0x7FFFu + ((u >> 16) & 1u)) >> 16);  // RNE
}

// two f32 -> packed bf16x2 (RNE), single HW instr on gfx950
__device__ __forceinline__ unsigned cvt_pk_bf16(float lo, float hi) {
  unsigned r;
  asm("v_cvt_pk_bf16_f32 %0, %1, %2" : "=v"(r) : "v"(lo), "v"(hi));
  return r;
}

// cross-half (lane ^ 32) reduce via permlane32_swap
__device__ __forceinline__ float xhalf_max(float v) {
  u32x2 r = __builtin_amdgcn_permlane32_swap(__float_as_uint(v), __float_as_uint(v), false, false);
  return fmaxf(__uint_as_float(r.x), __uint_as_float(r.y));
}
__device__ __forceinline__ float xhalf_sum(float v) {
  u32x2 r = __builtin_amdgcn_permlane32_swap(__float_as_uint(v), __float_as_uint(v), false, false);
  return __uint_as_float(r.x) + __uint_as_float(r.y);
}

// async global->LDS, 16B per lane; lds dest = wave-uniform base + lane*16
__device__ __forceinline__ void gll16(const ushort* g, ushort* l) {
  __builtin_amdgcn_global_load_lds(
      (const __attribute__((address_space(1))) unsigned*)g,
      (__attribute__((address_space(3))) unsigned*)l, 16, 0, 0);
}

// ---------- conversions ----------
__global__ __launch_bounds__(256) void cvt_f32_bf16(const float* __restrict__ in,
                                                    ushort* __restrict__ out, int n8) {
  int i = blockIdx.x * 256 + threadIdx.x;
  if (i >= n8) return;
  const f32x4* p = (const f32x4*)(in + (size_t)i * 8);
  f32x4 a = p[0], b = p[1];
  s16x8 o;
  o[0]=(short)f2b(a[0]); o[1]=(short)f2b(a[1]); o[2]=(short)f2b(a[2]); o[3]=(short)f2b(a[3]);
  o[4]=(short)f2b(b[0]); o[5]=(short)f2b(b[1]); o[6]=(short)f2b(b[2]); o[7]=(short)f2b(b[3]);
  *(s16x8*)(out + (size_t)i * 8) = o;
}

// All four weight transposes in one launch: Wt[n][k] = W[k][n], bf16 (1024x1024 each)
__global__ __launch_bounds__(256) void transpose_cvt4(const float* __restrict__ W0,
                                                      const float* __restrict__ W1,
                                                      const float* __restrict__ W2,
                                                      const float* __restrict__ W3,
                                                      ushort* __restrict__ Wt3,
                                                      ushort* __restrict__ Wot) {
  __shared__ float tile[32][33];
  int z = blockIdx.z;
  const float* W = (z == 0) ? W0 : (z == 1) ? W1 : (z == 2) ? W2 : W3;
  ushort* Wt = (z < 3) ? (Wt3 + (size_t)z * 1024 * 1024) : Wot;
  int nb = blockIdx.x * 32, kb = blockIdx.y * 32;
  int tx = threadIdx.x & 31, ty = threadIdx.x >> 5;  // 32 x 8
  #pragma unroll
  for (int j = ty; j < 32; j += 8) tile[j][tx] = W[(size_t)(kb + j) * 1024 + nb + tx];
  __syncthreads();
  #pragma unroll
  for (int j = ty; j < 32; j += 8) Wt[(size_t)(nb + j) * 1024 + kb + tx] = f2b(tile[tx][j]);
}

// ---------- fused QKV projection GEMM (m97 structure, BK=64) ----------
// C[4096 x 3072] = Xb @ W (Wt is B^T). LDS linear [128][64], global_load_lds w=16.
__global__ __launch_bounds__(256) void gemm_qkv(const ushort* __restrict__ Xb,
                                                const ushort* __restrict__ Wt,
                                                ushort* __restrict__ Qb,
                                                ushort* __restrict__ Kb,
                                                ushort* __restrict__ Vt) {
  __shared__ ushort Al[128 * 64];
  __shared__ ushort Bl[128 * 64];
  int tid = threadIdx.x, lane = tid & 63;
  int wid = tid >> 6;
  int wr = wid >> 1, wc = wid & 1, g = lane >> 4, c = lane & 15;
  int m0 = blockIdx.y * 128, n0 = blockIdx.x * 128;
  int r8 = tid >> 3, part = tid & 7;          // 32 rows / 8 parts per j-step
  int wbase = (tid & ~63) * 8;                // wave-uniform LDS ushort offset
  f32x4 acc[4][4] = {};
  for (int k0 = 0; k0 < DIN; k0 += 64) {
    __syncthreads();                          // prior reads done; safe to overwrite
    #pragma unroll
    for (int j = 0; j < 4; ++j) {
      gll16(&Xb[(size_t)(m0 + r8 + 32 * j) * DIN + k0 + part * 8], &Al[wbase + j * 2048]);
      gll16(&Wt[(size_t)(n0 + r8 + 32 * j) * DIN + k0 + part * 8], &Bl[wbase + j * 2048]);
    }
    __syncthreads();                          // vmcnt(0) drained before barrier
    #pragma unroll
    for (int kk = 0; kk < 2; ++kk) {
      s16x8 af[4], bfr[4];
      #pragma unroll
      for (int i = 0; i < 4; ++i) {
        af[i]  = *(const s16x8*)&Al[(wr * 64 + i * 16 + c) * 64 + kk * 32 + g * 8];
        bfr[i] = *(const s16x8*)&Bl[(wc * 64 + i * 16 + c) * 64 + kk * 32 + g * 8];
      }
      #pragma unroll
      for (int i = 0; i < 4; ++i)
        #pragma unroll
        for (int jn = 0; jn < 4; ++jn)
          acc[i][jn] = __builtin_amdgcn_mfma_f32_16x16x32_bf16(af[i], bfr[jn], acc[i][jn], 0, 0, 0);
    }
  }
  #pragma unroll
  for (int i = 0; i < 4; ++i)
    #pragma unroll
    for (int jn = 0; jn < 4; ++jn) {
      int mrow = m0 + wr * 64 + i * 16 + g * 4;
      int n = n0 + wc * 64 + jn * 16 + c;
      int b = mrow >> 11, t = mrow & (TT - 1);
      int which = n >> 10, nn = n & 1023, h = nn >> 6, d = nn & 63;
      size_t bh = (size_t)(b * NH + h);
      if (which == 2) {                              // V -> Vt[b][h][d][t]
        s16x4 pk;
        pk[0]=(short)f2b(acc[i][jn][0]); pk[1]=(short)f2b(acc[i][jn][1]);
        pk[2]=(short)f2b(acc[i][jn][2]); pk[3]=(short)f2b(acc[i][jn][3]);
        *(s16x4*)&Vt[(bh * HD + d) * TT + t] = pk;
      } else {
        // Q: fold softmax scale AND log2(e) (base-2 softmax downstream)
        float sc = (which == 0) ? 0.125f * 1.44269504f : 1.0f;
        ushort* dst = (which == 0) ? &Qb[(bh * TT + t) * HD + d]
                                   : &Kb[(bh * TT + t) * HD + d];
        #pragma unroll
        for (int r = 0; r < 4; ++r) dst[(size_t)r * HD] = f2b(acc[i][jn][r] * sc);
      }
    }
}

// ---------- causal flash attention: split-KV, KVBLK=64, XCD bh-locality ----------
__global__ __launch_bounds__(256, 2) void attn_fwd(const ushort* __restrict__ Qb,
                                                   const ushort* __restrict__ Kb,
                                                   const ushort* __restrict__ Vt,
                                                   ushort* __restrict__ Ctx) {
  __shared__ __align__(16) char smem[17920];
  int L = blockIdx.x;
  int xcd = L & 7, j = L >> 3;
  int bh = xcd + 8 * (j & 3);
  int qc = 63 - (j >> 2);                            // long blocks first
  int q0 = qc * 32;
  const ushort* Qh = Qb + (size_t)bh * TT * HD;
  const ushort* Kh = Kb + (size_t)bh * TT * HD;
  const ushort* Vh = Vt + (size_t)bh * HD * TT;
  int tid = threadIdx.x, lane = tid & 63, w = tid >> 6;
  int hi = lane >> 5, c32 = lane & 31;
  int q_abs = q0 + c32;
  int nt64 = (q0 + 32 + 63) >> 6;                    // 64-wide kv tiles

  ushort* pw = (ushort*)smem + w * (32 * PSTR2);

  s16x8 qf[4];
  #pragma unroll
  for (int s = 0; s < 4; ++s)
    qf[s] = *(const s16x8*)&Qh[(size_t)q_abs * HD + s * 16 + 8 * hi];

  f32x16 cA[2] = {};
  float m = -INFINITY, l = 0.f;

  s16x8 kfc[8];
  {
    int tt = (w < nt64) ? w : 0;
    #pragma unroll
    for (int ss = 0; ss < 2; ++ss)
      #pragma unroll
      for (int s = 0; s < 4; ++s)
        kfc[ss * 4 + s] =
            *(const s16x8*)&Kh[(size_t)(tt * 64 + ss * 32 + c32) * HD + s * 16 + 8 * hi];
  }

  for (int t = w; t < nt64; t += 4) {
    int kv0 = t * 64;
    s16x8 vf[2][4];
    #pragma unroll
    for (int dt = 0; dt < 2; ++dt)
      #pragma unroll
      for (int ks = 0; ks < 4; ++ks)
        vf[dt][ks] = *(const s16x8*)&Vh[(size_t)(dt * 32 + c32) * TT + kv0 + ks * 16 + 8 * hi];
    f32x16 S0 = {}, S1 = {};
    #pragma unroll
    for (int s = 0; s < 4; ++s)
      S0 = __builtin_amdgcn_mfma_f32_32x32x16_bf16(kfc[s], qf[s], S0, 0, 0, 0);
    #pragma unroll
    for (int s = 0; s < 4; ++s)
      S1 = __builtin_amdgcn_mfma_f32_32x32x16_bf16(kfc[4 + s], qf[s], S1, 0, 0, 0);
    if (t + 4 < nt64) {
      #pragma unroll
      for (int ss = 0; ss < 2; ++ss)
        #pragma unroll
        for (int s = 0; s < 4; ++s)
          kfc[ss * 4 + s] =
              *(const s16x8*)&Kh[(size_t)((t + 4) * 64 + ss * 32 + c32) * HD + s * 16 + 8 * hi];
    }
    if (kv0 + 63 > q0) {
      #pragma unroll
      for (int r = 0; r < 16; ++r) {
        int base = kv0 + (r & 3) + 8 * (r >> 2) + 4 * hi;
        S0[r] = (base > q_abs) ? -INFINITY : S0[r];
        S1[r] = (base + 32 > q_abs) ? -INFINITY : S1[r];
      }
    }
    float mx[8];
    #pragma unroll
    for (int i = 0; i < 8; ++i)
      mx[i] = fmaxf(fmaxf(S0[2 * i], S0[2 * i + 1]), fmaxf(S1[2 * i], S1[2 * i + 1]));
    #pragma unroll
    for (int i = 0; i < 4; ++i) mx[i] = fmaxf(mx[i], mx[i + 4]);
    mx[0] = fmaxf(fmaxf(mx[0], mx[2]), fmaxf(mx[1], mx[3]));
    float tmax = xhalf_max(mx[0]);
    if (__any(tmax > m + 8.f)) {
      float mnew = fmaxf(m, tmax);
      float alpha = exp2f(m - mnew);
      l *= alpha;
      #pragma unroll
      for (int dt = 0; dt < 2; ++dt)
        #pragma unroll
        for (int r = 0; r < 16; ++r) cA[dt][r] *= alpha;
      m = mnew;
    }
    #pragma unroll
    for (int r = 0; r < 16; ++r) { S0[r] = exp2f(S0[r] - m); S1[r] = exp2f(S1[r] - m); }
    float sm[8];
    #pragma unroll
    for (int i = 0; i < 8; ++i)
      sm[i] = (S0[2 * i] + S0[2 * i + 1]) + (S1[2 * i] + S1[2 * i + 1]);
    #pragma unroll
    for (int i = 0; i < 4; ++i) sm[i] += sm[i + 4];
    float rsum = (sm[0] + sm[2]) + (sm[1] + sm[3]);
    l += xhalf_sum(rsum);
    #pragma unroll
    for (int jj = 0; jj < 8; ++jj) {
      int kvb = ((2 * jj) & 3) + 8 * (jj >> 1) + 4 * hi;
      *(unsigned*)&pw[c32 * PSTR2 + kvb]      = cvt_pk_bf16(S0[2 * jj], S0[2 * jj + 1]);
      *(unsigned*)&pw[c32 * PSTR2 + 32 + kvb] = cvt_pk_bf16(S1[2 * jj], S1[2 * jj + 1]);
    }
    asm volatile("s_waitcnt lgkmcnt(0)" ::: "memory");
    #pragma unroll
    for (int ks = 0; ks < 4; ++ks) {
      s16x8 pf = *(const s16x8*)&pw[c32 * PSTR2 + ks * 16 + 8 * hi];
      cA[0] = __builtin_amdgcn_mfma_f32_32x32x16_bf16(vf[0][ks], pf, cA[0], 0, 0, 0);
      cA[1] = __builtin_amdgcn_mfma_f32_32x32x16_bf16(vf[1][ks], pf, cA[1], 0, 0, 0);
    }
  }

  __syncthreads();
  float* cb = (float*)smem;                // [4][32][20]
  float* mb = (float*)(smem + 10240);      // [4][32]
  float* lb = mb + 128;                    // [4][32]
  if (!hi) { mb[w * 32 + c32] = m; lb[w * 32 + c32] = l; }
  __syncthreads();

  int q  = tid >> 3;
  int dp = (tid & 7) * 2;
  float ew[4];
  {
    float mw[4];
    #pragma unroll
    for (int ww = 0; ww < 4; ++ww) mw[ww] = mb[ww * 32 + q];
    float mG = fmaxf(fmaxf(mw[0], mw[1]), fmaxf(mw[2], mw[3]));
    float lt = 0.f;
    #pragma unroll
    for (int ww = 0; ww < 4; ++ww) {
      ew[ww] = exp2f(mw[ww] - mG);
      lt += ew[ww] * lb[ww * 32 + q];
    }
    float inv = 1.f / lt;
    #pragma unroll
    for (int ww = 0; ww < 4; ++ww) ew[ww] *= inv;
  }
  int b = bh >> 4, h = bh & 15;
  #pragma unroll
  for (int rd = 0; rd < 4; ++rd) {
    int dt = rd >> 1, rh = rd & 1;
    float* dstq = &cb[(size_t)(w * 32 + c32) * 20];
    f32x4 v0 = { cA[dt][rh * 8 + 0], cA[dt][rh * 8 + 1], cA[dt][rh * 8 + 2], cA[dt][rh * 8 + 3] };
    f32x4 v1 = { cA[dt][rh * 8 + 4], cA[dt][rh * 8 + 5], cA[dt][rh * 8 + 6], cA[dt][rh * 8 + 7] };
    *(f32x4*)&dstq[4 * hi]     = v0;
    *(f32x4*)&dstq[8 + 4 * hi] = v1;
    __syncthreads();
    float s0 = 0.f, s1 = 0.f;
    #pragma unroll
    for (int ww = 0; ww < 4; ++ww) {
      const float* src = &cb[(size_t)(ww * 32 + q) * 20 + dp];
      s0 += ew[ww] * src[0];
      s1 += ew[ww] * src[1];
    }
    int dcol = h * HD + 32 * dt + 16 * rh + dp;
    *(unsigned*)&Ctx[((size_t)(b * TT) + q0 + q) * DIN + dcol] = cvt_pk_bf16(s0, s1);
    if (rd < 3) __syncthreads();
  }
}

// ---------- output projection + bias, fp32 out (BK=64, 128x64 tile, 2 blocks/CU) ----------
__global__ __launch_bounds__(256) void gemm_out(const ushort* __restrict__ Cb,
                                                const ushort* __restrict__ Wot,
                                                const float* __restrict__ bo,
                                                float* __restrict__ Out) {
  __shared__ ushort Al[128 * 64];
  __shared__ ushort Bl[64 * 64];
  int tid = threadIdx.x, lane = tid & 63;
  int wid = tid >> 6;
  int wr = wid >> 1, wc = wid & 1, g = lane >> 4, c = lane & 15;
  int m0 = blockIdx.y * 128, n0 = blockIdx.x * 64;
  int r8 = tid >> 3, part = tid & 7;
  int wbase = (tid & ~63) * 8;
  f32x4 acc[4][2] = {};
  for (int k0 = 0; k0 < DIN; k0 += 64) {
    __syncthreads();
    #pragma unroll
    for (int j = 0; j < 4; ++j)
      gll16(&Cb[(size_t)(m0 + r8 + 32 * j) * DIN + k0 + part * 8], &Al[wbase + j * 2048]);
    #pragma unroll
    for (int j = 0; j < 2; ++j)
      gll16(&Wot[(size_t)(n0 + r8 + 32 * j) * DIN + k0 + part * 8], &Bl[wbase + j * 2048]);
    __syncthreads();
    #pragma unroll
    for (int kk = 0; kk < 2; ++kk) {
      s16x8 af[4], bfr[2];
      #pragma unroll
      for (int i = 0; i < 4; ++i)
        af[i] = *(const s16x8*)&Al[(wr * 64 + i * 16 + c) * 64 + kk * 32 + g * 8];
      #pragma unroll
      for (int jn = 0; jn < 2; ++jn)
        bfr[jn] = *(const s16x8*)&Bl[(wc * 32 + jn * 16 + c) * 64 + kk * 32 + g * 8];
      #pragma unroll
      for (int i = 0; i < 4; ++i)
        #pragma unroll
        for (int jn = 0; jn < 2; ++jn)
          acc[i][jn] = __builtin_amdgcn_mfma_f32_16x16x32_bf16(af[i], bfr[jn], acc[i][jn], 0, 0, 0);
    }
  }
  #pragma unroll
  for (int i = 0; i < 4; ++i)
    #pragma unroll
    for (int jn = 0; jn < 2; ++jn) {
      int mrow = m0 + wr * 64 + i * 16 + g * 4;
      int n = n0 + wc * 32 + jn * 16 + c;
      float bias = bo[n];
      float* dst = &Out[(size_t)mrow * DIN + n];
      #pragma unroll
      for (int r = 0; r < 4; ++r) dst[(size_t)r * DIN] = acc[i][jn][r] + bias;
    }
}

extern "C" void kernel_launch(void* const* d_in, const int* in_sizes, int n_in,
                              void* d_out, int out_size, void* d_ws, size_t ws_size,
                              hipStream_t stream) {
  const float* x  = (const float*)d_in[0];
  const float* Wq = (const float*)d_in[1];
  const float* Wk = (const float*)d_in[2];
  const float* Wv = (const float*)d_in[3];
  const float* Wo = (const float*)d_in[4];
  const float* bo = (const float*)d_in[5];
  float* Out = (float*)d_out;

  char* ws = (char*)d_ws;
  size_t off = 0;
  auto alloc = [&](size_t bytes) -> char* {
    char* p = ws + off;
    off += (bytes + 255) & ~(size_t)255;
    return p;
  };
  ushort* Xb  = (ushort*)alloc((size_t)M_TOK * DIN * 2);
  ushort* Wt3 = (ushort*)alloc((size_t)3 * 1024 * DIN * 2);
  ushort* Wot = (ushort*)alloc((size_t)1024 * 1024 * 2);
  ushort* Qb  = (ushort*)alloc((size_t)NB * NH * TT * HD * 2);
  ushort* Kb  = (ushort*)alloc((size_t)NB * NH * TT * HD * 2);
  ushort* Vt  = (ushort*)alloc((size_t)NB * NH * TT * HD * 2);
  ushort* Cb  = (ushort*)alloc((size_t)M_TOK * DIN * 2);

  cvt_f32_bf16<<<(M_TOK * DIN / 8 + 255) / 256, 256, 0, stream>>>(x, Xb, M_TOK * DIN / 8);
  transpose_cvt4<<<dim3(32, 32, 4), 256, 0, stream>>>(Wq, Wk, Wv, Wo, Wt3, Wot);

  gemm_qkv<<<dim3(3072 / 128, M_TOK / 128), 256, 0, stream>>>(Xb, Wt3, Qb, Kb, Vt);
  attn_fwd<<<2048, 256, 0, stream>>>(Qb, Kb, Vt, Cb);
  gemm_out<<<dim3(1024 / 64, M_TOK / 128), 256, 0, stream>>>(Cb, Wot, bo, Out);
}